// Round 15
// baseline (298.489 us; speedup 1.0000x reference)
//
#include <hip/hip_runtime.h>

typedef unsigned short u16;
typedef __attribute__((ext_vector_type(8))) short bf16x8;
typedef __attribute__((ext_vector_type(8))) unsigned short u16x8;
typedef __attribute__((ext_vector_type(4))) float f32x4;

__device__ __forceinline__ u16 f2bf(float f) {
  unsigned u = __builtin_bit_cast(unsigned, f);
  u += 0x7fffu + ((u >> 16) & 1u);
  return (u16)(u >> 16);
}
__device__ __forceinline__ float bf2f(u16 h) {
  unsigned u = ((unsigned)h) << 16;
  return __builtin_bit_cast(float, u);
}

#define NB 2048
#define NF 100
#define NE 64
#define NO 256
#define OCH 64
#define EMB_ST 72
#define EMBT_ST 136
#define GAW_ST 136

#define GLOAD16(gsrc, ldst)                                                        \
  __builtin_amdgcn_global_load_lds(                                                \
      (const __attribute__((address_space(1))) unsigned int*)(gsrc),               \
      (__attribute__((address_space(3))) unsigned int*)(ldst), 16, 0, 0)

// ---- prep (merged): blocks 0..63 compute M = (query·Wb)*0.0625; rest cvt w1 ----
__global__ void k_prep(const float* __restrict__ wb, const float* __restrict__ q,
                       u16* __restrict__ mt, const float* __restrict__ w1,
                       u16* __restrict__ w1bf) {
  if (blockIdx.x < 64) {
    int idx = blockIdx.x * 256 + threadIdx.x;   // 16384 = 256*64
    int o = idx >> 6, e = idx & 63;
    float s = 0.f;
    for (int k = 0; k < 64; ++k) s = fmaf(q[o * 64 + k], wb[k * 64 + e], s);
    mt[idx] = f2bf(s * 0.0625f);   // folds DK^-0.5 (0.125) and (alpha-1) (0.5)
  } else {
    int i4 = ((blockIdx.x - 64) * 256 + threadIdx.x) * 4;
    float4 v = *(const float4*)(w1 + i4);
    ushort4 o;
    o.x = f2bf(v.x); o.y = f2bf(v.y); o.z = f2bf(v.z); o.w = f2bf(v.w);
    *(ushort4*)(w1bf + i4) = o;
  }
}

// ------- f32 -> bf16 with per-k scale: w0'[n][k] = bf16(w0[n][k] * scl[k>>6]) -------
__global__ void k_cvt_w0s(const float* __restrict__ in, const float* __restrict__ scl,
                          u16* __restrict__ out) {
  size_t i4 = ((size_t)blockIdx.x * 256 + threadIdx.x) * 4;
  int o = (int)((i4 >> 6) & 255);
  float sc = scl[o];
  float4 v = *(const float4*)(in + i4);
  ushort4 u;
  u.x = f2bf(v.x * sc); u.y = f2bf(v.y * sc);
  u.z = f2bf(v.z * sc); u.w = f2bf(v.w * sc);
  *(ushort4*)(out + i4) = u;
}

// ------- fused gather + (per-o-chunk: gates GEMM + entmax + arm GEMM + exp-1) -------
// Wave-local phases (R13): each wave owns its 16 o-rows end-to-end; 2 barriers total.
__global__ __launch_bounds__(256) void k_mega(
    const int* __restrict__ ids, const float* __restrict__ vals,
    const float* __restrict__ etab, const u16* __restrict__ mt,
    const float* __restrict__ att, u16* __restrict__ tbuf,
    float* __restrict__ pstatB) {
  __shared__ u16 s_emb[112][EMB_ST];     // [f][e], rows 100..111 zero
  __shared__ u16 s_embT[64][EMBT_ST];    // [e][f], cols 100..135 zero
  __shared__ u16 s_gaw[64][GAW_ST];      // gates, then p*att (wave-local rows)
  __shared__ float s_rs[64];             // per-row 1/sum(p) (wave-local)
  __shared__ float s_ps[256][2];         // per-o {sum, sumsq} over e for this b

  const int tid = threadIdx.x;
  const int lane = tid & 63;
  const int wid = tid >> 6;
  const int b = blockIdx.x;

  // phase 0: gather emb = emb_table[ids]*clip(v)  (once per b; cross-wave)
  for (int f = wid; f < NF; f += 4) {
    int id = ids[b * NF + f];
    float v = vals[b * NF + f];
    v = fminf(fmaxf(v, 0.001f), 1.0f);
    float ev = etab[(size_t)id * NE + lane] * v;
    u16 bf = f2bf(ev);
    s_emb[f][lane] = bf;
    s_embT[lane][f] = bf;
  }
  for (int i = tid; i < 12 * EMB_ST; i += 256) s_emb[100 + i / EMB_ST][i % EMB_ST] = 0;
  for (int i = tid; i < 64 * 36; i += 256) s_embT[i / 36][100 + i % 36] = 0;
  for (int i = tid; i < 64 * 24; i += 256) s_gaw[i / 24][112 + i % 24] = 0;
  __syncthreads();   // s_emb/s_embT/s_gaw-pad visible to all waves (read-only after)

  for (int oc = 0; oc < 4; ++oc) {
    const int obase = oc * OCH;
    bf16x8 amt[2];
#pragma unroll
    for (int kh = 0; kh < 2; ++kh)
      amt[kh] = *(const bf16x8*)(mt + ((obase + wid * 16 + (lane & 15)) * 64 +
                                       kh * 32 + ((lane >> 4) * 8)));

    // phase 1: gates[o][f] = M[o,:]·emb[f,:]  (writes wave-local s_gaw rows)
#pragma unroll
    for (int ft = 0; ft < 7; ++ft) {
      f32x4 acc = {0.f, 0.f, 0.f, 0.f};
#pragma unroll
      for (int kh = 0; kh < 2; ++kh) {
        bf16x8 bfr = *(const bf16x8*)&s_emb[ft * 16 + (lane & 15)][kh * 32 + ((lane >> 4) * 8)];
        acc = __builtin_amdgcn_mfma_f32_16x16x32_bf16(amt[kh], bfr, acc, 0, 0, 0);
      }
      int fc = ft * 16 + (lane & 15);
      if (fc < NF) {
#pragma unroll
        for (int i = 0; i < 4; ++i)
          s_gaw[wid * 16 + ((lane >> 4) * 4) + i][fc] = f2bf(acc[i]);
      }
    }
    asm volatile("" ::: "memory");   // pin phase-1 writes before phase-2 reads (same wave)

    // phase 2: entmax(alpha=1.5), Newton x5 + rcp; quad per o-row, WAVE-LOCAL rows
    {
      const int q = lane & 3;
      const int rl = lane >> 2;            // 0..15 within wave's slice
      const int r = wid * 16 + rl;         // s_gaw/s_rs row (this wave's)
      const int og = obase + r;
      float x[28];
#pragma unroll
      for (int j = 0; j < 7; ++j) {
        ushort4 g = *(const ushort4*)&s_gaw[r][j * 16 + q * 4];
        x[j * 4 + 0] = bf2f(g.x); x[j * 4 + 1] = bf2f(g.y);
        x[j * 4 + 2] = bf2f(g.z); x[j * 4 + 3] = bf2f(g.w);
      }
      if (q > 0) { x[24] = -1e30f; x[25] = -1e30f; x[26] = -1e30f; x[27] = -1e30f; }
      float attv[28];
#pragma unroll
      for (int j = 0; j < 7; ++j) {
        if (j < 6 || q == 0) {
          float4 av = *(const float4*)(att + og * NF + j * 16 + q * 4);
          attv[j * 4 + 0] = av.x; attv[j * 4 + 1] = av.y;
          attv[j * 4 + 2] = av.z; attv[j * 4 + 3] = av.w;
        } else {
          attv[j * 4 + 0] = 0.f; attv[j * 4 + 1] = 0.f;
          attv[j * 4 + 2] = 0.f; attv[j * 4 + 3] = 0.f;
        }
      }
      float m0 = x[0], m1 = x[1];
#pragma unroll
      for (int j = 2; j < 28; j += 2) { m0 = fmaxf(m0, x[j]); m1 = fmaxf(m1, x[j + 1]); }
      float mx = fmaxf(m0, m1);
      mx = fmaxf(mx, __shfl_xor(mx, 1));
      mx = fmaxf(mx, __shfl_xor(mx, 2));
      float tau = mx - 1.0f;
#pragma unroll
      for (int it = 0; it < 5; ++it) {
        float s0 = 0.f, s1 = 0.f, t0 = 0.f, t1 = 0.f;
#pragma unroll
        for (int j = 0; j < 14; ++j) {
          float d0 = fmaxf(x[j] - tau, 0.f);
          float d1 = fmaxf(x[j + 14] - tau, 0.f);
          s0 = fmaf(d0, d0, s0); s1 = fmaf(d1, d1, s1);
          t0 += d0; t1 += d1;
        }
        float s = s0 + s1, sd = t0 + t1;
        s += __shfl_xor(s, 1);
        s += __shfl_xor(s, 2);
        sd += __shfl_xor(sd, 1);
        sd += __shfl_xor(sd, 2);
        float den = 2.0f * sd + 1e-30f;
        float inv;
        asm("v_rcp_f32 %0, %1" : "=v"(inv) : "v"(den));
        tau += (s - 1.0f) * inv;
      }
      float s0 = 0.f, s1 = 0.f;
#pragma unroll
      for (int j = 0; j < 14; ++j) {
        float d0 = fmaxf(x[j] - tau, 0.f);
        float d1 = fmaxf(x[j + 14] - tau, 0.f);
        x[j] = d0 * d0;
        x[j + 14] = d1 * d1;
        s0 += x[j]; s1 += x[j + 14];
      }
      float s = s0 + s1;
      s += __shfl_xor(s, 1);
      s += __shfl_xor(s, 2);
      if (q == 0) s_rs[r] = 1.0f / s;
#pragma unroll
      for (int j = 0; j < 7; ++j) {
        ushort4 w;
        w.x = f2bf(x[j * 4 + 0] * attv[j * 4 + 0]);
        w.y = f2bf(x[j * 4 + 1] * attv[j * 4 + 1]);
        w.z = f2bf(x[j * 4 + 2] * attv[j * 4 + 2]);
        w.w = f2bf(x[j * 4 + 3] * attv[j * 4 + 3]);
        *(ushort4*)&s_gaw[r][j * 16 + q * 4] = w;
      }
    }
    asm volatile("" ::: "memory");   // pin phase-2 writes before phase-3 reads (same wave)

    // phase 3: arm[o][e] = rs[o] * sum_f aw[o][f]*emb[f][e];  t = exp(arm)-1
    f32x4 acc[4] = {};
#pragma unroll
    for (int h = 0; h < 4; ++h) {
      bf16x8 afr = *(const bf16x8*)&s_gaw[wid * 16 + (lane & 15)][h * 32 + ((lane >> 4) * 8)];
#pragma unroll
      for (int et = 0; et < 4; ++et) {
        bf16x8 bfr = *(const bf16x8*)&s_embT[et * 16 + (lane & 15)][h * 32 + ((lane >> 4) * 8)];
        acc[et] = __builtin_amdgcn_mfma_f32_16x16x32_bf16(afr, bfr, acc[et], 0, 0, 0);
      }
    }
    const int rloc = wid * 16 + ((lane >> 4) * 4);
    float rs4[4];
#pragma unroll
    for (int i = 0; i < 4; ++i) rs4[i] = s_rs[rloc + i];
    float tval[4][4];   // [et][i]
#pragma unroll
    for (int et = 0; et < 4; ++et)
#pragma unroll
      for (int i = 0; i < 4; ++i)
        tval[et][i] = __expf(acc[et][i] * rs4[i]) - 1.0f;
    size_t orow = (size_t)b * NO + obase + rloc;
#pragma unroll
    for (int et = 0; et < 4; ++et) {
      int e = et * 16 + (lane & 15);
#pragma unroll
      for (int i = 0; i < 4; ++i)
        tbuf[(orow + i) * 64 + e] = f2bf(tval[et][i]);
    }
    // fused BN partials: per row, sum over e (4 et cols here x 16 lanes of group)
#pragma unroll
    for (int i = 0; i < 4; ++i) {
      float sp = tval[0][i] + tval[1][i] + tval[2][i] + tval[3][i];
      float sq = fmaf(tval[0][i], tval[0][i],
                 fmaf(tval[1][i], tval[1][i],
                 fmaf(tval[2][i], tval[2][i], tval[3][i] * tval[3][i])));
#pragma unroll
      for (int m = 1; m < 16; m <<= 1) {
        sp += __shfl_xor(sp, m);
        sq += __shfl_xor(sq, m);
      }
      if ((lane & 15) == 0) {
        s_ps[obase + rloc + i][0] = sp;
        s_ps[obase + rloc + i][1] = sq;
      }
    }
    asm volatile("" ::: "memory");   // pin phase-3 reads before next-oc phase-1 writes
  }
  __syncthreads();   // s_ps is read cross-wave below
  // write per-block BN partials (coalesced: 256 threads x float2)
  *(float2*)&pstatB[(size_t)b * 512 + tid * 2] =
      make_float2(s_ps[tid][0], s_ps[tid][1]);
}

// ------- per-o BN scale: fold 2048 block partials -> scl = g*rsqrt(var+eps) -------
__global__ void k_stats_o_fin2(const float* __restrict__ pstatB,
                               const float* __restrict__ g, float* __restrict__ scl) {
  const int o = blockIdx.x;
  float s = 0.f, s2 = 0.f;
  for (int bb = threadIdx.x; bb < NB; bb += 256) {
    float2 v = *(const float2*)&pstatB[(size_t)bb * 512 + o * 2];
    s += v.x; s2 += v.y;
  }
  __shared__ float red[2][256];
  red[0][threadIdx.x] = s; red[1][threadIdx.x] = s2;
  __syncthreads();
  for (int st = 128; st >= 1; st >>= 1) {
    if (threadIdx.x < st) {
      red[0][threadIdx.x] += red[0][threadIdx.x + st];
      red[1][threadIdx.x] += red[1][threadIdx.x + st];
    }
    __syncthreads();
  }
  if (threadIdx.x == 0) {
    float invN = 1.0f / (float)(NB * 64);
    float m = red[0][0] * invN;
    float var = red[1][0] * invN - m * m;
    scl[o] = g[o] * rsqrtf(var + 1e-5f);
  }
}

// ---- pipelined bf16 GEMM, C[m][n] = sum_k A[m][k]*B[n][k] (B^T layout), split-K ----
// BM=BN=128, BK=32, 4 waves (2x2). RING-6 as 3 ping-pong PAIRS (48KB LDS ->
// 3 blocks/CU): per sync-pair consume 2 K-tiles (32 MFMA), 4 tiles in flight.
// Invariant at loop top: 16 issues outstanding (tiles jj+2..jj+5), pair jj landed.
// After staging tiles jj+6,jj+7 into the just-freed pair: 24 outstanding;
// vmcnt(16) -> tiles jj+2,jj+3 landed. Prologue: 24 issues (tiles 0..5),
// vmcnt(16). Tail: clamped dummy re-stages (post-barrier, race-free). nkt>=6, even.
__global__ __launch_bounds__(256, 3) void k_gemmp(const u16* __restrict__ A,
                                                  const u16* __restrict__ B,
                                                  float* __restrict__ C,
                                                  int M, int N, int K, int ksz) {
  __shared__ u16 lds[6 * 8192];   // 6 slots x (A 128x32 + B 128x32) = 48KB
  const int tid = threadIdx.x, lane = tid & 63, wid = tid >> 6;
  const int wr = wid >> 1, wc = wid & 1;

  const int nx = gridDim.x, ny = gridDim.y;
  const int nwg = nx * ny * gridDim.z;
  int lin = blockIdx.x + nx * (blockIdx.y + ny * blockIdx.z);
  int swz = (lin & 7) * (nwg >> 3) + (lin >> 3);   // nwg % 8 == 0
  const int bx = swz % nx;
  const int byz = swz / nx;
  const int by = byz % ny, bz = byz / ny;

  const int m0 = bx * 128, n0 = by * 128;
  const int k0 = bz * ksz;
  C += (size_t)bz * ((size_t)M * N);

  f32x4 acc[4][4];
#pragma unroll
  for (int mi = 0; mi < 4; ++mi)
#pragma unroll
    for (int ni = 0; ni < 4; ++ni) acc[mi][ni] = (f32x4){0.f, 0.f, 0.f, 0.f};

  const int gchunk = (lane & 3) ^ ((lane >> 3) & 3);
  const u16* gstage = (wid < 2)
      ? A + (size_t)(m0 + wid * 64 + (lane >> 2)) * K + k0 + gchunk * 8
      : B + (size_t)(n0 + (wid - 2) * 64 + (lane >> 2)) * K + k0 + gchunk * 8;
  const int lstage = (wid < 2) ? (wid * 64) * 32 : 4096 + ((wid - 2) * 64) * 32;

  const int la15 = lane & 15, la4 = lane >> 4;
  int aoffs[4], boffs[4];
#pragma unroll
  for (int i = 0; i < 4; ++i) {
    int ra = wr * 64 + i * 16 + la15;
    aoffs[i] = ra * 32 + ((la4 ^ ((ra >> 1) & 3)) * 8);
    int rb = wc * 64 + i * 16 + la15;
    boffs[i] = 4096 + rb * 32 + ((la4 ^ ((rb >> 1) & 3)) * 8);
  }

  const int nkt = ksz / 32;
  // prologue: stage tiles 0..5 into slots 0..5 (24 issues/wave)
#pragma unroll
  for (int t = 0; t < 6; ++t)
#pragma unroll
    for (int i = 0; i < 4; ++i)
      GLOAD16(gstage + (size_t)t * 32 + (size_t)i * 16 * K, lds + t * 8192 + lstage + i * 512);
  asm volatile("s_waitcnt vmcnt(16)" ::: "memory");   // tiles 0,1 (mine) landed
  __builtin_amdgcn_sched_barrier(0);
  __builtin_amdgcn_s_barrier();                       // tiles 0,1 (everyone's) landed
  __builtin_amdgcn_sched_barrier(0);

  int pair = 0;   // pair p occupies slots {2p, 2p+1}; rotates 0,1,2
  for (int jj = 0; jj < nkt; jj += 2) {
    const int sa = pair * 16384, sb = sa + 8192;
    bf16x8 af0[4], bf0[4], af1[4], bf1[4];
#pragma unroll
    for (int i = 0; i < 4; ++i) {
      af0[i] = *(const bf16x8*)(lds + sa + aoffs[i]);
      bf0[i] = *(const bf16x8*)(lds + sa + boffs[i]);
      af1[i] = *(const bf16x8*)(lds + sb + aoffs[i]);
      bf1[i] = *(const bf16x8*)(lds + sb + boffs[i]);
    }
    asm volatile("s_waitcnt lgkmcnt(0)" ::: "memory");  // my reads of pair done
    __builtin_amdgcn_sched_barrier(0);
    __builtin_amdgcn_s_barrier();                       // all waves' reads done
    __builtin_amdgcn_sched_barrier(0);
    const int ts0 = (jj + 6 < nkt) ? jj + 6 : nkt - 1;  // tail: benign dummy re-stage
    const int ts1 = (jj + 7 < nkt) ? jj + 7 : nkt - 1;
#pragma unroll
    for (int i = 0; i < 4; ++i)
      GLOAD16(gstage + (size_t)ts0 * 32 + (size_t)i * 16 * K, lds + sa + lstage + i * 512);
#pragma unroll
    for (int i = 0; i < 4; ++i)
      GLOAD16(gstage + (size_t)ts1 * 32 + (size_t)i * 16 * K, lds + sb + lstage + i * 512);
    __builtin_amdgcn_s_setprio(1);
#pragma unroll
    for (int mi = 0; mi < 4; ++mi)
#pragma unroll
      for (int ni = 0; ni < 4; ++ni)
        acc[mi][ni] = __builtin_amdgcn_mfma_f32_16x16x32_bf16(af0[mi], bf0[ni], acc[mi][ni], 0, 0, 0);
#pragma unroll
    for (int mi = 0; mi < 4; ++mi)
#pragma unroll
      for (int ni = 0; ni < 4; ++ni)
        acc[mi][ni] = __builtin_amdgcn_mfma_f32_16x16x32_bf16(af1[mi], bf1[ni], acc[mi][ni], 0, 0, 0);
    __builtin_amdgcn_s_setprio(0);
    asm volatile("s_waitcnt vmcnt(16)" ::: "memory");   // tiles jj+2,jj+3 (mine) landed
    __builtin_amdgcn_sched_barrier(0);
    __builtin_amdgcn_s_barrier();                       // (everyone's) landed
    __builtin_amdgcn_sched_barrier(0);
    pair = (pair == 2) ? 0 : pair + 1;
  }

#pragma unroll
  for (int mi = 0; mi < 4; ++mi) {
    int m = m0 + wr * 64 + mi * 16 + ((lane >> 4) * 4);
#pragma unroll
    for (int ni = 0; ni < 4; ++ni) {
      int n = n0 + wc * 64 + ni * 16 + (lane & 15);
#pragma unroll
      for (int i = 0; i < 4; ++i) C[(size_t)(m + i) * N + n] = acc[mi][ni][i];
    }
  }
}

// ---- fused: r = sum of NP split-K partials  +  per-(rowgroup,col) BN partial stats ----
template <int NP>
__global__ void k_red_stats(const float* __restrict__ c, float* __restrict__ r,
                            float* __restrict__ pstat) {
  const int col = blockIdx.x * 64 + (threadIdx.x & 63);
  const int rt = threadIdx.x >> 6;
  const int rg = blockIdx.y;
  const size_t ps = (size_t)NB * 1024;
  float s = 0.f, s2 = 0.f;
  for (int rr = rt; rr < 64; rr += 4) {
    size_t idx = (size_t)(rg * 64 + rr) * 1024 + col;
    float v = c[idx];
#pragma unroll
    for (int p = 1; p < NP; ++p) v += c[p * ps + idx];
    r[idx] = v;
    s += v;
    s2 = fmaf(v, v, s2);
  }
  __shared__ float red[2][256];
  red[0][threadIdx.x] = s; red[1][threadIdx.x] = s2;
  __syncthreads();
  if (threadIdx.x < 64) {
    int t = threadIdx.x;
    s  = red[0][t] + red[0][t + 64] + red[0][t + 128] + red[0][t + 192];
    s2 = red[1][t] + red[1][t + 64] + red[1][t + 128] + red[1][t + 192];
    pstat[((size_t)rg * 1024 + col) * 2]     = s;
    pstat[((size_t)rg * 1024 + col) * 2 + 1] = s2;
  }
}

// ---- finalize col BN: fold 32 rowgroup partials -> scl/bia ----
__global__ void k_stats_fin(const float* __restrict__ pstat,
                            const float* __restrict__ g, const float* __restrict__ be,
                            float* __restrict__ scl, float* __restrict__ bia) {
  int col = blockIdx.x * 256 + threadIdx.x;
  float s = 0.f, s2 = 0.f;
#pragma unroll
  for (int p = 0; p < 32; ++p) {
    s  += pstat[((size_t)p * 1024 + col) * 2];
    s2 += pstat[((size_t)p * 1024 + col) * 2 + 1];
  }
  float invN = 1.0f / (float)NB;
  float m = s * invN;
  float var = s2 * invN - m * m;
  float inv = rsqrtf(var + 1e-5f);
  scl[col] = g[col] * inv;
  bia[col] = be[col] - g[col] * inv * m;
}

// ---------------- a1 = bf16(relu(r0*scl + bia)) ----------------
__global__ void k_applyA1(const float* __restrict__ c0,
                          const float* __restrict__ scl, const float* __restrict__ bia,
                          u16* __restrict__ a1) {
  size_t i4 = ((size_t)blockIdx.x * 256 + threadIdx.x) * 4;
  int n = (int)(i4 & 1023);
  float4 v0 = *(const float4*)(c0 + i4);
  ushort4 o;
  o.x = f2bf(fmaxf(fmaf(v0.x, scl[n + 0], bia[n + 0]), 0.f));
  o.y = f2bf(fmaxf(fmaf(v0.y, scl[n + 1], bia[n + 1]), 0.f));
  o.z = f2bf(fmaxf(fmaf(v0.z, scl[n + 2], bia[n + 2]), 0.f));
  o.w = f2bf(fmaxf(fmaf(v0.w, scl[n + 3], bia[n + 3]), 0.f));
  *(ushort4*)(a1 + i4) = o;
}

// -------- y[b] = out_b + sum_n relu(h*scl+bia)*out_w[n] --------
__global__ void k_final(const float* __restrict__ h, const float* __restrict__ scl,
                        const float* __restrict__ bia, const float* __restrict__ ow,
                        const float* __restrict__ ob, float* __restrict__ y) {
  int lane = threadIdx.x & 63, wid = threadIdx.x >> 6;
  int row = blockIdx.x * 4 + wid;
  const float* hr = h + (size_t)row * 1024;
  float part = 0.f;
#pragma unroll
  for (int j = 0; j < 16; ++j) {
    int n = j * 64 + lane;
    float v = fmaxf(fmaf(hr[n], scl[n], bia[n]), 0.f);
    part = fmaf(v, ow[n], part);
  }
#pragma unroll
  for (int off = 32; off >= 1; off >>= 1) part += __shfl_xor(part, off);
  if (lane == 0) y[row] = part + ob[0];
}

extern "C" void kernel_launch(void* const* d_in, const int* in_sizes, int n_in,
                              void* d_out, int out_size, void* d_ws, size_t ws_size,
                              hipStream_t stream) {
  const int*   ids   = (const int*)d_in[0];
  const float* vals  = (const float*)d_in[1];
  const float* etab  = (const float*)d_in[2];
  const float* wb    = (const float*)d_in[3];
  const float* query = (const float*)d_in[4];
  const float* att   = (const float*)d_in[5];
  const float* bng   = (const float*)d_in[6];
  const float* w0    = (const float*)d_in[8];
  const float* g0    = (const float*)d_in[10];
  const float* be0   = (const float*)d_in[11];
  const float* w1    = (const float*)d_in[12];
  const float* g1    = (const float*)d_in[14];
  const float* be1   = (const float*)d_in[15];
  const float* outw  = (const float*)d_in[16];
  const float* outb  = (const float*)d_in[17];
  float* y = (float*)d_out;

  // workspace layout (peak ~195.6 MB):
  //   [0, 32K)            mt
  //   [32K, 33.59M)       w0bf (32MB, pre-scaled by arm-BN scl)
  //   [33.59M, 35.68M)    w1bf (2MB)
  //   [35.68M, 102.79M)   tbuf (64MB bf16)  -- alive through gemm0 (A operand)
  //   [102.79M, 134.87M)  c01 (4x8MB f32)   -- gemm0 partials; dead after red_stats<4>
  //   [102.79M, 134.87M)  h1 (4x8MB f32)    -- overlays dead c01; gemm1 partials
  //   [169.90M, 178.29M)  r0 (8MB f32)
  //   [178.29M, 182.48M)  a1 (4MB bf16)
  //   [182.48M, 186.68M)  pstatB (4MB, per-block o-stats) -- dead after fin2
  //   [186.68M, 195.07M)  h (8MB f32, summed)
  //   [195.07M, ...)      pstat1/pstat2 + BN scalars
  char* ws = (char*)d_ws;
  u16*   mt     = (u16*)(ws + 0);
  u16*   w0bf   = (u16*)(ws + 32768ull);
  u16*   w1bf   = (u16*)(ws + 33587200ull);
  u16*   tbuf   = (u16*)(ws + 35684352ull);
  float* c01    = (float*)(ws + 102793216ull);
  float* h1     = (float*)(ws + 102793216ull);
  float* r0     = (float*)(ws + 169902080ull);
  u16*   a1     = (u16*)(ws + 178290688ull);
  float* pstatB = (float*)(ws + 182484992ull);
  float* h      = (float*)(ws + 186679296ull);
  float* pstat1 = (float*)(ws + 195067904ull);
  float* pstat2 = (float*)(ws + 195330048ull);
  float* sclA   = (float*)(ws + 195608576ull);
  float* scl1   = (float*)(ws + 195609600ull);
  float* bia1   = (float*)(ws + 195613696ull);
  float* scl2   = (float*)(ws + 195617792ull);
  float* bia2   = (float*)(ws + 195621888ull);

  k_prep<<<1088, 256, 0, stream>>>(wb, query, mt, w1, w1bf);
  k_mega<<<2048, 256, 0, stream>>>(ids, vals, etab, mt, att, tbuf, pstatB);
  k_stats_o_fin2<<<256, 256, 0, stream>>>(pstatB, bng, sclA);
  k_cvt_w0s<<<16384, 256, 0, stream>>>(w0, sclA, w0bf);
  // gemm0: ring-6 (3 pairs, 48KB -> 3 blocks/CU), split-K=4 -> 512 blocks, ksz=4096 (nkt=128)
  k_gemmp<<<dim3(16, 8, 4), 256, 0, stream>>>(tbuf, w0bf, c01, 2048, 1024, 16384, 4096);
  k_red_stats<4><<<dim3(16, 32), 256, 0, stream>>>(c01, r0, pstat1);
  k_stats_fin<<<4, 256, 0, stream>>>(pstat1, g0, be0, scl1, bia1);
  k_applyA1<<<2048, 256, 0, stream>>>(r0, scl1, bia1, a1);
  // gemm1: same kernel, split-K=4 -> 512 blocks, ksz=256 (nkt=8)
  k_gemmp<<<dim3(16, 8, 4), 256, 0, stream>>>(a1, w1bf, h1, 2048, 1024, 1024, 256);
  k_red_stats<4><<<dim3(16, 32), 256, 0, stream>>>(h1, h, pstat2);
  k_stats_fin<<<4, 256, 0, stream>>>(pstat2, g1, be1, scl2, bia2);
  k_final<<<512, 256, 0, stream>>>(h, scl2, bia2, outw, outb, y);
}

// Round 16
// 253.293 us; speedup vs baseline: 1.1784x; 1.1784x over previous
//
#include <hip/hip_runtime.h>

typedef unsigned short u16;
typedef __attribute__((ext_vector_type(8))) short bf16x8;
typedef __attribute__((ext_vector_type(8))) unsigned short u16x8;
typedef __attribute__((ext_vector_type(4))) float f32x4;

__device__ __forceinline__ u16 f2bf(float f) {
  unsigned u = __builtin_bit_cast(unsigned, f);
  u += 0x7fffu + ((u >> 16) & 1u);
  return (u16)(u >> 16);
}
__device__ __forceinline__ float bf2f(u16 h) {
  unsigned u = ((unsigned)h) << 16;
  return __builtin_bit_cast(float, u);
}

#define NB 2048
#define NF 100
#define NE 64
#define NO 256
#define OCH 64
#define EMB_ST 72
#define EMBT_ST 136
#define GAW_ST 136

#define GLOAD16(gsrc, ldst)                                                        \
  __builtin_amdgcn_global_load_lds(                                                \
      (const __attribute__((address_space(1))) unsigned int*)(gsrc),               \
      (__attribute__((address_space(3))) unsigned int*)(ldst), 16, 0, 0)

// ---- prep (merged): blocks 0..63 compute M = (query·Wb)*0.0625; rest cvt w1 ----
__global__ void k_prep(const float* __restrict__ wb, const float* __restrict__ q,
                       u16* __restrict__ mt, const float* __restrict__ w1,
                       u16* __restrict__ w1bf) {
  if (blockIdx.x < 64) {
    int idx = blockIdx.x * 256 + threadIdx.x;   // 16384 = 256*64
    int o = idx >> 6, e = idx & 63;
    float s = 0.f;
    for (int k = 0; k < 64; ++k) s = fmaf(q[o * 64 + k], wb[k * 64 + e], s);
    mt[idx] = f2bf(s * 0.0625f);   // folds DK^-0.5 (0.125) and (alpha-1) (0.5)
  } else {
    int i4 = ((blockIdx.x - 64) * 256 + threadIdx.x) * 4;
    float4 v = *(const float4*)(w1 + i4);
    ushort4 o;
    o.x = f2bf(v.x); o.y = f2bf(v.y); o.z = f2bf(v.z); o.w = f2bf(v.w);
    *(ushort4*)(w1bf + i4) = o;
  }
}

// ------- f32 -> bf16 with per-k scale: w0'[n][k] = bf16(w0[n][k] * scl[k>>6]) -------
__global__ void k_cvt_w0s(const float* __restrict__ in, const float* __restrict__ scl,
                          u16* __restrict__ out) {
  size_t i4 = ((size_t)blockIdx.x * 256 + threadIdx.x) * 4;
  int o = (int)((i4 >> 6) & 255);
  float sc = scl[o];
  float4 v = *(const float4*)(in + i4);
  ushort4 u;
  u.x = f2bf(v.x * sc); u.y = f2bf(v.y * sc);
  u.z = f2bf(v.z * sc); u.w = f2bf(v.w * sc);
  *(ushort4*)(out + i4) = u;
}

// ------- fused gather + (per-o-chunk: gates GEMM + entmax + arm GEMM + exp-1) -------
// Wave-local phases (R13): each wave owns its 16 o-rows end-to-end; 2 barriers total.
__global__ __launch_bounds__(256) void k_mega(
    const int* __restrict__ ids, const float* __restrict__ vals,
    const float* __restrict__ etab, const u16* __restrict__ mt,
    const float* __restrict__ att, u16* __restrict__ tbuf,
    float* __restrict__ pstatB) {
  __shared__ u16 s_emb[112][EMB_ST];     // [f][e], rows 100..111 zero
  __shared__ u16 s_embT[64][EMBT_ST];    // [e][f], cols 100..135 zero
  __shared__ u16 s_gaw[64][GAW_ST];      // gates, then p*att (wave-local rows)
  __shared__ float s_rs[64];             // per-row 1/sum(p) (wave-local)
  __shared__ float s_ps[256][2];         // per-o {sum, sumsq} over e for this b

  const int tid = threadIdx.x;
  const int lane = tid & 63;
  const int wid = tid >> 6;
  const int b = blockIdx.x;

  // phase 0: gather emb = emb_table[ids]*clip(v)  (once per b; cross-wave)
  for (int f = wid; f < NF; f += 4) {
    int id = ids[b * NF + f];
    float v = vals[b * NF + f];
    v = fminf(fmaxf(v, 0.001f), 1.0f);
    float ev = etab[(size_t)id * NE + lane] * v;
    u16 bf = f2bf(ev);
    s_emb[f][lane] = bf;
    s_embT[lane][f] = bf;
  }
  for (int i = tid; i < 12 * EMB_ST; i += 256) s_emb[100 + i / EMB_ST][i % EMB_ST] = 0;
  for (int i = tid; i < 64 * 36; i += 256) s_embT[i / 36][100 + i % 36] = 0;
  for (int i = tid; i < 64 * 24; i += 256) s_gaw[i / 24][112 + i % 24] = 0;
  __syncthreads();   // s_emb/s_embT/s_gaw-pad visible to all waves (read-only after)

  for (int oc = 0; oc < 4; ++oc) {
    const int obase = oc * OCH;
    bf16x8 amt[2];
#pragma unroll
    for (int kh = 0; kh < 2; ++kh)
      amt[kh] = *(const bf16x8*)(mt + ((obase + wid * 16 + (lane & 15)) * 64 +
                                       kh * 32 + ((lane >> 4) * 8)));

    // phase 1: gates[o][f] = M[o,:]·emb[f,:]  (writes wave-local s_gaw rows)
#pragma unroll
    for (int ft = 0; ft < 7; ++ft) {
      f32x4 acc = {0.f, 0.f, 0.f, 0.f};
#pragma unroll
      for (int kh = 0; kh < 2; ++kh) {
        bf16x8 bfr = *(const bf16x8*)&s_emb[ft * 16 + (lane & 15)][kh * 32 + ((lane >> 4) * 8)];
        acc = __builtin_amdgcn_mfma_f32_16x16x32_bf16(amt[kh], bfr, acc, 0, 0, 0);
      }
      int fc = ft * 16 + (lane & 15);
      if (fc < NF) {
#pragma unroll
        for (int i = 0; i < 4; ++i)
          s_gaw[wid * 16 + ((lane >> 4) * 4) + i][fc] = f2bf(acc[i]);
      }
    }
    asm volatile("" ::: "memory");   // pin phase-1 writes before phase-2 reads (same wave)

    // phase 2: entmax(alpha=1.5), Newton x5 + rcp; quad per o-row, WAVE-LOCAL rows
    {
      const int q = lane & 3;
      const int rl = lane >> 2;            // 0..15 within wave's slice
      const int r = wid * 16 + rl;         // s_gaw/s_rs row (this wave's)
      const int og = obase + r;
      float x[28];
#pragma unroll
      for (int j = 0; j < 7; ++j) {
        ushort4 g = *(const ushort4*)&s_gaw[r][j * 16 + q * 4];
        x[j * 4 + 0] = bf2f(g.x); x[j * 4 + 1] = bf2f(g.y);
        x[j * 4 + 2] = bf2f(g.z); x[j * 4 + 3] = bf2f(g.w);
      }
      if (q > 0) { x[24] = -1e30f; x[25] = -1e30f; x[26] = -1e30f; x[27] = -1e30f; }
      float attv[28];
#pragma unroll
      for (int j = 0; j < 7; ++j) {
        if (j < 6 || q == 0) {
          float4 av = *(const float4*)(att + og * NF + j * 16 + q * 4);
          attv[j * 4 + 0] = av.x; attv[j * 4 + 1] = av.y;
          attv[j * 4 + 2] = av.z; attv[j * 4 + 3] = av.w;
        } else {
          attv[j * 4 + 0] = 0.f; attv[j * 4 + 1] = 0.f;
          attv[j * 4 + 2] = 0.f; attv[j * 4 + 3] = 0.f;
        }
      }
      float m0 = x[0], m1 = x[1];
#pragma unroll
      for (int j = 2; j < 28; j += 2) { m0 = fmaxf(m0, x[j]); m1 = fmaxf(m1, x[j + 1]); }
      float mx = fmaxf(m0, m1);
      mx = fmaxf(mx, __shfl_xor(mx, 1));
      mx = fmaxf(mx, __shfl_xor(mx, 2));
      float tau = mx - 1.0f;
#pragma unroll
      for (int it = 0; it < 5; ++it) {
        float s0 = 0.f, s1 = 0.f, t0 = 0.f, t1 = 0.f;
#pragma unroll
        for (int j = 0; j < 14; ++j) {
          float d0 = fmaxf(x[j] - tau, 0.f);
          float d1 = fmaxf(x[j + 14] - tau, 0.f);
          s0 = fmaf(d0, d0, s0); s1 = fmaf(d1, d1, s1);
          t0 += d0; t1 += d1;
        }
        float s = s0 + s1, sd = t0 + t1;
        s += __shfl_xor(s, 1);
        s += __shfl_xor(s, 2);
        sd += __shfl_xor(sd, 1);
        sd += __shfl_xor(sd, 2);
        float den = 2.0f * sd + 1e-30f;
        float inv;
        asm("v_rcp_f32 %0, %1" : "=v"(inv) : "v"(den));
        tau += (s - 1.0f) * inv;
      }
      float s0 = 0.f, s1 = 0.f;
#pragma unroll
      for (int j = 0; j < 14; ++j) {
        float d0 = fmaxf(x[j] - tau, 0.f);
        float d1 = fmaxf(x[j + 14] - tau, 0.f);
        x[j] = d0 * d0;
        x[j + 14] = d1 * d1;
        s0 += x[j]; s1 += x[j + 14];
      }
      float s = s0 + s1;
      s += __shfl_xor(s, 1);
      s += __shfl_xor(s, 2);
      if (q == 0) s_rs[r] = 1.0f / s;
#pragma unroll
      for (int j = 0; j < 7; ++j) {
        ushort4 w;
        w.x = f2bf(x[j * 4 + 0] * attv[j * 4 + 0]);
        w.y = f2bf(x[j * 4 + 1] * attv[j * 4 + 1]);
        w.z = f2bf(x[j * 4 + 2] * attv[j * 4 + 2]);
        w.w = f2bf(x[j * 4 + 3] * attv[j * 4 + 3]);
        *(ushort4*)&s_gaw[r][j * 16 + q * 4] = w;
      }
    }
    asm volatile("" ::: "memory");   // pin phase-2 writes before phase-3 reads (same wave)

    // phase 3: arm[o][e] = rs[o] * sum_f aw[o][f]*emb[f][e];  t = exp(arm)-1
    f32x4 acc[4] = {};
#pragma unroll
    for (int h = 0; h < 4; ++h) {
      bf16x8 afr = *(const bf16x8*)&s_gaw[wid * 16 + (lane & 15)][h * 32 + ((lane >> 4) * 8)];
#pragma unroll
      for (int et = 0; et < 4; ++et) {
        bf16x8 bfr = *(const bf16x8*)&s_embT[et * 16 + (lane & 15)][h * 32 + ((lane >> 4) * 8)];
        acc[et] = __builtin_amdgcn_mfma_f32_16x16x32_bf16(afr, bfr, acc[et], 0, 0, 0);
      }
    }
    const int rloc = wid * 16 + ((lane >> 4) * 4);
    float rs4[4];
#pragma unroll
    for (int i = 0; i < 4; ++i) rs4[i] = s_rs[rloc + i];
    float tval[4][4];   // [et][i]
#pragma unroll
    for (int et = 0; et < 4; ++et)
#pragma unroll
      for (int i = 0; i < 4; ++i)
        tval[et][i] = __expf(acc[et][i] * rs4[i]) - 1.0f;
    size_t orow = (size_t)b * NO + obase + rloc;
#pragma unroll
    for (int et = 0; et < 4; ++et) {
      int e = et * 16 + (lane & 15);
#pragma unroll
      for (int i = 0; i < 4; ++i)
        tbuf[(orow + i) * 64 + e] = f2bf(tval[et][i]);
    }
    // fused BN partials: per row, sum over e (4 et cols here x 16 lanes of group)
#pragma unroll
    for (int i = 0; i < 4; ++i) {
      float sp = tval[0][i] + tval[1][i] + tval[2][i] + tval[3][i];
      float sq = fmaf(tval[0][i], tval[0][i],
                 fmaf(tval[1][i], tval[1][i],
                 fmaf(tval[2][i], tval[2][i], tval[3][i] * tval[3][i])));
#pragma unroll
      for (int m = 1; m < 16; m <<= 1) {
        sp += __shfl_xor(sp, m);
        sq += __shfl_xor(sq, m);
      }
      if ((lane & 15) == 0) {
        s_ps[obase + rloc + i][0] = sp;
        s_ps[obase + rloc + i][1] = sq;
      }
    }
    asm volatile("" ::: "memory");   // pin phase-3 reads before next-oc phase-1 writes
  }
  __syncthreads();   // s_ps is read cross-wave below
  // write per-block BN partials (coalesced: 256 threads x float2)
  *(float2*)&pstatB[(size_t)b * 512 + tid * 2] =
      make_float2(s_ps[tid][0], s_ps[tid][1]);
}

// ------- per-o BN scale: fold 2048 block partials -> scl = g*rsqrt(var+eps) -------
__global__ void k_stats_o_fin2(const float* __restrict__ pstatB,
                               const float* __restrict__ g, float* __restrict__ scl) {
  const int o = blockIdx.x;
  float s = 0.f, s2 = 0.f;
  for (int bb = threadIdx.x; bb < NB; bb += 256) {
    float2 v = *(const float2*)&pstatB[(size_t)bb * 512 + o * 2];
    s += v.x; s2 += v.y;
  }
  __shared__ float red[2][256];
  red[0][threadIdx.x] = s; red[1][threadIdx.x] = s2;
  __syncthreads();
  for (int st = 128; st >= 1; st >>= 1) {
    if (threadIdx.x < st) {
      red[0][threadIdx.x] += red[0][threadIdx.x + st];
      red[1][threadIdx.x] += red[1][threadIdx.x + st];
    }
    __syncthreads();
  }
  if (threadIdx.x == 0) {
    float invN = 1.0f / (float)(NB * 64);
    float m = red[0][0] * invN;
    float var = red[1][0] * invN - m * m;
    scl[o] = g[o] * rsqrtf(var + 1e-5f);
  }
}

// ---- pipelined bf16 GEMM, C[m][n] = sum_k A[m][k]*B[n][k] (B^T layout), split-K ----
// BM=BN=128, BK=32, 4 waves (2x2), ring-4 LDS slots (64KB) as 2 ping-pong PAIRS
// (32 MFMA per sync-pair) + chunk-XOR bank swizzle (conflicts measured 0).
__global__ __launch_bounds__(256) void k_gemmp(const u16* __restrict__ A,
                                               const u16* __restrict__ B,
                                               float* __restrict__ C,
                                               int M, int N, int K, int ksz) {
  __shared__ u16 lds[4 * 8192];   // 4 slots x 16KB = 64KB
  const int tid = threadIdx.x, lane = tid & 63, wid = tid >> 6;
  const int wr = wid >> 1, wc = wid & 1;

  const int nx = gridDim.x, ny = gridDim.y;
  const int nwg = nx * ny * gridDim.z;
  int lin = blockIdx.x + nx * (blockIdx.y + ny * blockIdx.z);
  int swz = (lin & 7) * (nwg >> 3) + (lin >> 3);   // nwg % 8 == 0
  const int bx = swz % nx;
  const int byz = swz / nx;
  const int by = byz % ny, bz = byz / ny;

  const int m0 = bx * 128, n0 = by * 128;
  const int k0 = bz * ksz;
  C += (size_t)bz * ((size_t)M * N);

  f32x4 acc[4][4];
#pragma unroll
  for (int mi = 0; mi < 4; ++mi)
#pragma unroll
    for (int ni = 0; ni < 4; ++ni) acc[mi][ni] = (f32x4){0.f, 0.f, 0.f, 0.f};

  const int gchunk = (lane & 3) ^ ((lane >> 3) & 3);
  const u16* gstage = (wid < 2)
      ? A + (size_t)(m0 + wid * 64 + (lane >> 2)) * K + k0 + gchunk * 8
      : B + (size_t)(n0 + (wid - 2) * 64 + (lane >> 2)) * K + k0 + gchunk * 8;
  const int lstage = (wid < 2) ? (wid * 64) * 32 : 4096 + ((wid - 2) * 64) * 32;

  const int la15 = lane & 15, la4 = lane >> 4;
  int aoffs[4], boffs[4];
#pragma unroll
  for (int i = 0; i < 4; ++i) {
    int ra = wr * 64 + i * 16 + la15;
    aoffs[i] = ra * 32 + ((la4 ^ ((ra >> 1) & 3)) * 8);
    int rb = wc * 64 + i * 16 + la15;
    boffs[i] = 4096 + rb * 32 + ((la4 ^ ((rb >> 1) & 3)) * 8);
  }

  const int nkt = ksz / 32;
#pragma unroll
  for (int t = 0; t < 4; ++t)
#pragma unroll
    for (int i = 0; i < 4; ++i)
      GLOAD16(gstage + (size_t)t * 32 + (size_t)i * 16 * K, lds + t * 8192 + lstage + i * 512);
  asm volatile("s_waitcnt vmcnt(8)" ::: "memory");   // tiles 0,1 (mine) landed
  __builtin_amdgcn_sched_barrier(0);
  __builtin_amdgcn_s_barrier();                      // tiles 0,1 (everyone's) landed
  __builtin_amdgcn_sched_barrier(0);

  int pbase = 0;   // 0 -> slots {0,1}, 16384 -> slots {2,3}
  for (int jj = 0; jj < nkt; jj += 2) {
    const int sa = pbase, sb = pbase + 8192;
    bf16x8 af0[4], bf0[4], af1[4], bf1[4];
#pragma unroll
    for (int i = 0; i < 4; ++i) {
      af0[i] = *(const bf16x8*)(lds + sa + aoffs[i]);
      bf0[i] = *(const bf16x8*)(lds + sa + boffs[i]);
      af1[i] = *(const bf16x8*)(lds + sb + aoffs[i]);
      bf1[i] = *(const bf16x8*)(lds + sb + boffs[i]);
    }
    asm volatile("s_waitcnt lgkmcnt(0)" ::: "memory");  // my reads of both slots done
    __builtin_amdgcn_sched_barrier(0);
    __builtin_amdgcn_s_barrier();                       // all waves' reads done
    __builtin_amdgcn_sched_barrier(0);
    const int ts0 = (jj + 4 < nkt) ? jj + 4 : nkt - 1;  // tail: benign dummy re-stage
    const int ts1 = (jj + 5 < nkt) ? jj + 5 : nkt - 1;
#pragma unroll
    for (int i = 0; i < 4; ++i)
      GLOAD16(gstage + (size_t)ts0 * 32 + (size_t)i * 16 * K, lds + sa + lstage + i * 512);
#pragma unroll
    for (int i = 0; i < 4; ++i)
      GLOAD16(gstage + (size_t)ts1 * 32 + (size_t)i * 16 * K, lds + sb + lstage + i * 512);
    __builtin_amdgcn_s_setprio(1);
#pragma unroll
    for (int mi = 0; mi < 4; ++mi)
#pragma unroll
      for (int ni = 0; ni < 4; ++ni)
        acc[mi][ni] = __builtin_amdgcn_mfma_f32_16x16x32_bf16(af0[mi], bf0[ni], acc[mi][ni], 0, 0, 0);
#pragma unroll
    for (int mi = 0; mi < 4; ++mi)
#pragma unroll
      for (int ni = 0; ni < 4; ++ni)
        acc[mi][ni] = __builtin_amdgcn_mfma_f32_16x16x32_bf16(af1[mi], bf1[ni], acc[mi][ni], 0, 0, 0);
    __builtin_amdgcn_s_setprio(0);
    asm volatile("s_waitcnt vmcnt(8)" ::: "memory");    // tiles jj+2,jj+3 (mine) landed
    __builtin_amdgcn_sched_barrier(0);
    __builtin_amdgcn_s_barrier();                       // (everyone's) landed
    __builtin_amdgcn_sched_barrier(0);
    pbase ^= 16384;
  }

#pragma unroll
  for (int mi = 0; mi < 4; ++mi) {
    int m = m0 + wr * 64 + mi * 16 + ((lane >> 4) * 4);
#pragma unroll
    for (int ni = 0; ni < 4; ++ni) {
      int n = n0 + wc * 64 + ni * 16 + (lane & 15);
#pragma unroll
      for (int i = 0; i < 4; ++i) C[(size_t)(m + i) * N + n] = acc[mi][ni][i];
    }
  }
}

// ---- fused: r = sum of NP split-K partials  +  per-(rowgroup,col) BN partial stats ----
template <int NP>
__global__ void k_red_stats(const float* __restrict__ c, float* __restrict__ r,
                            float* __restrict__ pstat) {
  const int col = blockIdx.x * 64 + (threadIdx.x & 63);
  const int rt = threadIdx.x >> 6;
  const int rg = blockIdx.y;
  const size_t ps = (size_t)NB * 1024;
  float s = 0.f, s2 = 0.f;
  for (int rr = rt; rr < 64; rr += 4) {
    size_t idx = (size_t)(rg * 64 + rr) * 1024 + col;
    float v = c[idx];
#pragma unroll
    for (int p = 1; p < NP; ++p) v += c[p * ps + idx];
    r[idx] = v;
    s += v;
    s2 = fmaf(v, v, s2);
  }
  __shared__ float red[2][256];
  red[0][threadIdx.x] = s; red[1][threadIdx.x] = s2;
  __syncthreads();
  if (threadIdx.x < 64) {
    int t = threadIdx.x;
    s  = red[0][t] + red[0][t + 64] + red[0][t + 128] + red[0][t + 192];
    s2 = red[1][t] + red[1][t + 64] + red[1][t + 128] + red[1][t + 192];
    pstat[((size_t)rg * 1024 + col) * 2]     = s;
    pstat[((size_t)rg * 1024 + col) * 2 + 1] = s2;
  }
}

// ---- finalize col BN: fold 32 rowgroup partials -> scl/bia ----
__global__ void k_stats_fin(const float* __restrict__ pstat,
                            const float* __restrict__ g, const float* __restrict__ be,
                            float* __restrict__ scl, float* __restrict__ bia) {
  int col = blockIdx.x * 256 + threadIdx.x;
  float s = 0.f, s2 = 0.f;
#pragma unroll
  for (int p = 0; p < 32; ++p) {
    s  += pstat[((size_t)p * 1024 + col) * 2];
    s2 += pstat[((size_t)p * 1024 + col) * 2 + 1];
  }
  float invN = 1.0f / (float)NB;
  float m = s * invN;
  float var = s2 * invN - m * m;
  float inv = rsqrtf(var + 1e-5f);
  scl[col] = g[col] * inv;
  bia[col] = be[col] - g[col] * inv * m;
}

// ---------------- a1 = bf16(relu(r0*scl + bia)) ----------------
__global__ void k_applyA1(const float* __restrict__ c0,
                          const float* __restrict__ scl, const float* __restrict__ bia,
                          u16* __restrict__ a1) {
  size_t i4 = ((size_t)blockIdx.x * 256 + threadIdx.x) * 4;
  int n = (int)(i4 & 1023);
  float4 v0 = *(const float4*)(c0 + i4);
  ushort4 o;
  o.x = f2bf(fmaxf(fmaf(v0.x, scl[n + 0], bia[n + 0]), 0.f));
  o.y = f2bf(fmaxf(fmaf(v0.y, scl[n + 1], bia[n + 1]), 0.f));
  o.z = f2bf(fmaxf(fmaf(v0.z, scl[n + 2], bia[n + 2]), 0.f));
  o.w = f2bf(fmaxf(fmaf(v0.w, scl[n + 3], bia[n + 3]), 0.f));
  *(ushort4*)(a1 + i4) = o;
}

// -------- y[b] = out_b + sum_n relu(h*scl+bia)*out_w[n] --------
__global__ void k_final(const float* __restrict__ h, const float* __restrict__ scl,
                        const float* __restrict__ bia, const float* __restrict__ ow,
                        const float* __restrict__ ob, float* __restrict__ y) {
  int lane = threadIdx.x & 63, wid = threadIdx.x >> 6;
  int row = blockIdx.x * 4 + wid;
  const float* hr = h + (size_t)row * 1024;
  float part = 0.f;
#pragma unroll
  for (int j = 0; j < 16; ++j) {
    int n = j * 64 + lane;
    float v = fmaxf(fmaf(hr[n], scl[n], bia[n]), 0.f);
    part = fmaf(v, ow[n], part);
  }
#pragma unroll
  for (int off = 32; off >= 1; off >>= 1) part += __shfl_xor(part, off);
  if (lane == 0) y[row] = part + ob[0];
}

extern "C" void kernel_launch(void* const* d_in, const int* in_sizes, int n_in,
                              void* d_out, int out_size, void* d_ws, size_t ws_size,
                              hipStream_t stream) {
  const int*   ids   = (const int*)d_in[0];
  const float* vals  = (const float*)d_in[1];
  const float* etab  = (const float*)d_in[2];
  const float* wb    = (const float*)d_in[3];
  const float* query = (const float*)d_in[4];
  const float* att   = (const float*)d_in[5];
  const float* bng   = (const float*)d_in[6];
  const float* w0    = (const float*)d_in[8];
  const float* g0    = (const float*)d_in[10];
  const float* be0   = (const float*)d_in[11];
  const float* w1    = (const float*)d_in[12];
  const float* g1    = (const float*)d_in[14];
  const float* be1   = (const float*)d_in[15];
  const float* outw  = (const float*)d_in[16];
  const float* outb  = (const float*)d_in[17];
  float* y = (float*)d_out;

  // workspace layout (peak ~195.6 MB):
  //   [0, 32K)            mt
  //   [32K, 33.59M)       w0bf (32MB, pre-scaled by arm-BN scl)
  //   [33.59M, 35.68M)    w1bf (2MB)
  //   [35.68M, 102.79M)   tbuf (64MB bf16)  -- alive through gemm0 (A operand)
  //   [102.79M, 134.87M)  c01 (4x8MB f32)   -- gemm0 partials; dead after red_stats<4>
  //   [102.79M, 134.87M)  h1 (4x8MB f32)    -- overlays dead c01; gemm1 partials
  //   [169.90M, 178.29M)  r0 (8MB f32)
  //   [178.29M, 182.48M)  a1 (4MB bf16)
  //   [182.48M, 186.68M)  pstatB (4MB, per-block o-stats) -- dead after fin2
  //   [186.68M, 195.07M)  h (8MB f32, summed)
  //   [195.07M, ...)      pstat1/pstat2 + BN scalars
  char* ws = (char*)d_ws;
  u16*   mt     = (u16*)(ws + 0);
  u16*   w0bf   = (u16*)(ws + 32768ull);
  u16*   w1bf   = (u16*)(ws + 33587200ull);
  u16*   tbuf   = (u16*)(ws + 35684352ull);
  float* c01    = (float*)(ws + 102793216ull);
  float* h1     = (float*)(ws + 102793216ull);
  float* r0     = (float*)(ws + 169902080ull);
  u16*   a1     = (u16*)(ws + 178290688ull);
  float* pstatB = (float*)(ws + 182484992ull);
  float* h      = (float*)(ws + 186679296ull);
  float* pstat1 = (float*)(ws + 195067904ull);
  float* pstat2 = (float*)(ws + 195330048ull);
  float* sclA   = (float*)(ws + 195608576ull);
  float* scl1   = (float*)(ws + 195609600ull);
  float* bia1   = (float*)(ws + 195613696ull);
  float* scl2   = (float*)(ws + 195617792ull);
  float* bia2   = (float*)(ws + 195621888ull);

  k_prep<<<1088, 256, 0, stream>>>(wb, query, mt, w1, w1bf);
  k_mega<<<2048, 256, 0, stream>>>(ids, vals, etab, mt, att, tbuf, pstatB);
  k_stats_o_fin2<<<256, 256, 0, stream>>>(pstatB, bng, sclA);
  k_cvt_w0s<<<16384, 256, 0, stream>>>(w0, sclA, w0bf);
  // gemm0: ring-4 (64KB, 2/CU), 2-tile-per-sync, split-K=4 -> 512 blocks, ksz=4096 (nkt=128)
  k_gemmp<<<dim3(16, 8, 4), 256, 0, stream>>>(tbuf, w0bf, c01, 2048, 1024, 16384, 4096);
  k_red_stats<4><<<dim3(16, 32), 256, 0, stream>>>(c01, r0, pstat1);
  k_stats_fin<<<4, 256, 0, stream>>>(pstat1, g0, be0, scl1, bia1);
  k_applyA1<<<2048, 256, 0, stream>>>(r0, scl1, bia1, a1);
  // gemm1: same kernel, split-K=4 -> 512 blocks, ksz=256 (nkt=8)
  k_gemmp<<<dim3(16, 8, 4), 256, 0, stream>>>(a1, w1bf, h1, 2048, 1024, 1024, 256);
  k_red_stats<4><<<dim3(16, 32), 256, 0, stream>>>(h1, h, pstat2);
  k_stats_fin<<<4, 256, 0, stream>>>(pstat2, g1, be1, scl2, bia2);
  k_final<<<512, 256, 0, stream>>>(h, scl2, bia2, outw, outb, y);
}

// Round 17
// 245.986 us; speedup vs baseline: 1.2134x; 1.0297x over previous
//
#include <hip/hip_runtime.h>

typedef unsigned short u16;
typedef __attribute__((ext_vector_type(8))) short bf16x8;
typedef __attribute__((ext_vector_type(8))) unsigned short u16x8;
typedef __attribute__((ext_vector_type(4))) float f32x4;

__device__ __forceinline__ u16 f2bf(float f) {
  unsigned u = __builtin_bit_cast(unsigned, f);
  u += 0x7fffu + ((u >> 16) & 1u);
  return (u16)(u >> 16);
}
__device__ __forceinline__ float bf2f(u16 h) {
  unsigned u = ((unsigned)h) << 16;
  return __builtin_bit_cast(float, u);
}

#define NB 2048
#define NF 100
#define NE 64
#define NO 256
#define OCH 64
#define EMB_ST 72
#define EMBT_ST 136
#define GAW_ST 136

#define GLOAD16(gsrc, ldst)                                                        \
  __builtin_amdgcn_global_load_lds(                                                \
      (const __attribute__((address_space(1))) unsigned int*)(gsrc),               \
      (__attribute__((address_space(3))) unsigned int*)(ldst), 16, 0, 0)

// ---- prep (merged): blocks 0..63 compute M = (query·Wb)*0.0625; rest cvt w1 ----
__global__ void k_prep(const float* __restrict__ wb, const float* __restrict__ q,
                       u16* __restrict__ mt, const float* __restrict__ w1,
                       u16* __restrict__ w1bf) {
  if (blockIdx.x < 64) {
    int idx = blockIdx.x * 256 + threadIdx.x;   // 16384 = 256*64
    int o = idx >> 6, e = idx & 63;
    float s = 0.f;
    for (int k = 0; k < 64; ++k) s = fmaf(q[o * 64 + k], wb[k * 64 + e], s);
    mt[idx] = f2bf(s * 0.0625f);   // folds DK^-0.5 (0.125) and (alpha-1) (0.5)
  } else {
    int i4 = ((blockIdx.x - 64) * 256 + threadIdx.x) * 4;
    float4 v = *(const float4*)(w1 + i4);
    ushort4 o;
    o.x = f2bf(v.x); o.y = f2bf(v.y); o.z = f2bf(v.z); o.w = f2bf(v.w);
    *(ushort4*)(w1bf + i4) = o;
  }
}

// ------- f32 -> bf16 with per-k scale: w0'[n][k] = bf16(w0[n][k] * scl[k>>6]) -------
__global__ void k_cvt_w0s(const float* __restrict__ in, const float* __restrict__ scl,
                          u16* __restrict__ out) {
  size_t i4 = ((size_t)blockIdx.x * 256 + threadIdx.x) * 4;
  int o = (int)((i4 >> 6) & 255);
  float sc = scl[o];
  float4 v = *(const float4*)(in + i4);
  ushort4 u;
  u.x = f2bf(v.x * sc); u.y = f2bf(v.y * sc);
  u.z = f2bf(v.z * sc); u.w = f2bf(v.w * sc);
  *(ushort4*)(out + i4) = u;
}

// ------- fused gather + (per-o-chunk: gates GEMM + entmax + arm GEMM + exp-1) -------
// Wave-local phases (R13): each wave owns its 16 o-rows end-to-end; 2 barriers total.
__global__ __launch_bounds__(256) void k_mega(
    const int* __restrict__ ids, const float* __restrict__ vals,
    const float* __restrict__ etab, const u16* __restrict__ mt,
    const float* __restrict__ att, u16* __restrict__ tbuf,
    float* __restrict__ pstatB) {
  __shared__ u16 s_emb[112][EMB_ST];     // [f][e], rows 100..111 zero
  __shared__ u16 s_embT[64][EMBT_ST];    // [e][f], cols 100..135 zero
  __shared__ u16 s_gaw[64][GAW_ST];      // gates, then p*att (wave-local rows)
  __shared__ float s_rs[64];             // per-row 1/sum(p) (wave-local)
  __shared__ float s_ps[256][2];         // per-o {sum, sumsq} over e for this b

  const int tid = threadIdx.x;
  const int lane = tid & 63;
  const int wid = tid >> 6;
  const int b = blockIdx.x;

  // phase 0: gather emb = emb_table[ids]*clip(v)  (once per b; cross-wave)
  for (int f = wid; f < NF; f += 4) {
    int id = ids[b * NF + f];
    float v = vals[b * NF + f];
    v = fminf(fmaxf(v, 0.001f), 1.0f);
    float ev = etab[(size_t)id * NE + lane] * v;
    u16 bf = f2bf(ev);
    s_emb[f][lane] = bf;
    s_embT[lane][f] = bf;
  }
  for (int i = tid; i < 12 * EMB_ST; i += 256) s_emb[100 + i / EMB_ST][i % EMB_ST] = 0;
  for (int i = tid; i < 64 * 36; i += 256) s_embT[i / 36][100 + i % 36] = 0;
  for (int i = tid; i < 64 * 24; i += 256) s_gaw[i / 24][112 + i % 24] = 0;
  __syncthreads();   // s_emb/s_embT/s_gaw-pad visible to all waves (read-only after)

  for (int oc = 0; oc < 4; ++oc) {
    const int obase = oc * OCH;
    bf16x8 amt[2];
#pragma unroll
    for (int kh = 0; kh < 2; ++kh)
      amt[kh] = *(const bf16x8*)(mt + ((obase + wid * 16 + (lane & 15)) * 64 +
                                       kh * 32 + ((lane >> 4) * 8)));

    // phase 1: gates[o][f] = M[o,:]·emb[f,:]  (writes wave-local s_gaw rows)
#pragma unroll
    for (int ft = 0; ft < 7; ++ft) {
      f32x4 acc = {0.f, 0.f, 0.f, 0.f};
#pragma unroll
      for (int kh = 0; kh < 2; ++kh) {
        bf16x8 bfr = *(const bf16x8*)&s_emb[ft * 16 + (lane & 15)][kh * 32 + ((lane >> 4) * 8)];
        acc = __builtin_amdgcn_mfma_f32_16x16x32_bf16(amt[kh], bfr, acc, 0, 0, 0);
      }
      int fc = ft * 16 + (lane & 15);
      if (fc < NF) {
#pragma unroll
        for (int i = 0; i < 4; ++i)
          s_gaw[wid * 16 + ((lane >> 4) * 4) + i][fc] = f2bf(acc[i]);
      }
    }
    asm volatile("" ::: "memory");   // pin phase-1 writes before phase-2 reads (same wave)

    // phase 2: entmax(alpha=1.5), Newton x4 + rcp; quad per o-row, WAVE-LOCAL rows.
    // Newton from tau0=mx-1 is monotone on the convex decreasing f; after 4 iters
    // the residual tau error is common-mode (shared per row) and cancels in the
    // final normalization to first order (absmax invariant across 22-bisect ->
    // Newton-5 -> Newton-4 supports this).
    {
      const int q = lane & 3;
      const int rl = lane >> 2;            // 0..15 within wave's slice
      const int r = wid * 16 + rl;         // s_gaw/s_rs row (this wave's)
      const int og = obase + r;
      float x[28];
#pragma unroll
      for (int j = 0; j < 7; ++j) {
        ushort4 g = *(const ushort4*)&s_gaw[r][j * 16 + q * 4];
        x[j * 4 + 0] = bf2f(g.x); x[j * 4 + 1] = bf2f(g.y);
        x[j * 4 + 2] = bf2f(g.z); x[j * 4 + 3] = bf2f(g.w);
      }
      if (q > 0) { x[24] = -1e30f; x[25] = -1e30f; x[26] = -1e30f; x[27] = -1e30f; }
      float attv[28];
#pragma unroll
      for (int j = 0; j < 7; ++j) {
        if (j < 6 || q == 0) {
          float4 av = *(const float4*)(att + og * NF + j * 16 + q * 4);
          attv[j * 4 + 0] = av.x; attv[j * 4 + 1] = av.y;
          attv[j * 4 + 2] = av.z; attv[j * 4 + 3] = av.w;
        } else {
          attv[j * 4 + 0] = 0.f; attv[j * 4 + 1] = 0.f;
          attv[j * 4 + 2] = 0.f; attv[j * 4 + 3] = 0.f;
        }
      }
      float m0 = x[0], m1 = x[1];
#pragma unroll
      for (int j = 2; j < 28; j += 2) { m0 = fmaxf(m0, x[j]); m1 = fmaxf(m1, x[j + 1]); }
      float mx = fmaxf(m0, m1);
      mx = fmaxf(mx, __shfl_xor(mx, 1));
      mx = fmaxf(mx, __shfl_xor(mx, 2));
      float tau = mx - 1.0f;
#pragma unroll
      for (int it = 0; it < 4; ++it) {
        float s0 = 0.f, s1 = 0.f, t0 = 0.f, t1 = 0.f;
#pragma unroll
        for (int j = 0; j < 14; ++j) {
          float d0 = fmaxf(x[j] - tau, 0.f);
          float d1 = fmaxf(x[j + 14] - tau, 0.f);
          s0 = fmaf(d0, d0, s0); s1 = fmaf(d1, d1, s1);
          t0 += d0; t1 += d1;
        }
        float s = s0 + s1, sd = t0 + t1;
        s += __shfl_xor(s, 1);
        s += __shfl_xor(s, 2);
        sd += __shfl_xor(sd, 1);
        sd += __shfl_xor(sd, 2);
        float den = 2.0f * sd + 1e-30f;
        float inv;
        asm("v_rcp_f32 %0, %1" : "=v"(inv) : "v"(den));
        tau += (s - 1.0f) * inv;
      }
      float s0 = 0.f, s1 = 0.f;
#pragma unroll
      for (int j = 0; j < 14; ++j) {
        float d0 = fmaxf(x[j] - tau, 0.f);
        float d1 = fmaxf(x[j + 14] - tau, 0.f);
        x[j] = d0 * d0;
        x[j + 14] = d1 * d1;
        s0 += x[j]; s1 += x[j + 14];
      }
      float s = s0 + s1;
      s += __shfl_xor(s, 1);
      s += __shfl_xor(s, 2);
      if (q == 0) s_rs[r] = 1.0f / s;
#pragma unroll
      for (int j = 0; j < 7; ++j) {
        ushort4 w;
        w.x = f2bf(x[j * 4 + 0] * attv[j * 4 + 0]);
        w.y = f2bf(x[j * 4 + 1] * attv[j * 4 + 1]);
        w.z = f2bf(x[j * 4 + 2] * attv[j * 4 + 2]);
        w.w = f2bf(x[j * 4 + 3] * attv[j * 4 + 3]);
        *(ushort4*)&s_gaw[r][j * 16 + q * 4] = w;
      }
    }
    asm volatile("" ::: "memory");   // pin phase-2 writes before phase-3 reads (same wave)

    // phase 3: arm[o][e] = rs[o] * sum_f aw[o][f]*emb[f][e];  t = exp(arm)-1
    f32x4 acc[4] = {};
#pragma unroll
    for (int h = 0; h < 4; ++h) {
      bf16x8 afr = *(const bf16x8*)&s_gaw[wid * 16 + (lane & 15)][h * 32 + ((lane >> 4) * 8)];
#pragma unroll
      for (int et = 0; et < 4; ++et) {
        bf16x8 bfr = *(const bf16x8*)&s_embT[et * 16 + (lane & 15)][h * 32 + ((lane >> 4) * 8)];
        acc[et] = __builtin_amdgcn_mfma_f32_16x16x32_bf16(afr, bfr, acc[et], 0, 0, 0);
      }
    }
    const int rloc = wid * 16 + ((lane >> 4) * 4);
    float rs4[4];
#pragma unroll
    for (int i = 0; i < 4; ++i) rs4[i] = s_rs[rloc + i];
    float tval[4][4];   // [et][i]
#pragma unroll
    for (int et = 0; et < 4; ++et)
#pragma unroll
      for (int i = 0; i < 4; ++i)
        tval[et][i] = __expf(acc[et][i] * rs4[i]) - 1.0f;
    size_t orow = (size_t)b * NO + obase + rloc;
#pragma unroll
    for (int et = 0; et < 4; ++et) {
      int e = et * 16 + (lane & 15);
#pragma unroll
      for (int i = 0; i < 4; ++i)
        tbuf[(orow + i) * 64 + e] = f2bf(tval[et][i]);
    }
    // fused BN partials: per row, sum over e (4 et cols here x 16 lanes of group)
#pragma unroll
    for (int i = 0; i < 4; ++i) {
      float sp = tval[0][i] + tval[1][i] + tval[2][i] + tval[3][i];
      float sq = fmaf(tval[0][i], tval[0][i],
                 fmaf(tval[1][i], tval[1][i],
                 fmaf(tval[2][i], tval[2][i], tval[3][i] * tval[3][i])));
#pragma unroll
      for (int m = 1; m < 16; m <<= 1) {
        sp += __shfl_xor(sp, m);
        sq += __shfl_xor(sq, m);
      }
      if ((lane & 15) == 0) {
        s_ps[obase + rloc + i][0] = sp;
        s_ps[obase + rloc + i][1] = sq;
      }
    }
    asm volatile("" ::: "memory");   // pin phase-3 reads before next-oc phase-1 writes
  }
  __syncthreads();   // s_ps is read cross-wave below
  // write per-block BN partials (coalesced: 256 threads x float2)
  *(float2*)&pstatB[(size_t)b * 512 + tid * 2] =
      make_float2(s_ps[tid][0], s_ps[tid][1]);
}

// ---- per-o BN stage A: sum 64 bb-rows of pstatB, fully coalesced ----
// grid 32; block g covers rows [g*64, g*64+64); thread t owns column pair t*2
// (o = t): consecutive threads read consecutive float2 -> 2KB contiguous/row.
__global__ void k_stats_oA(const float* __restrict__ pstatB, float* __restrict__ p2) {
  const int g = blockIdx.x, t = threadIdx.x;
  float s = 0.f, s2 = 0.f;
  for (int bb = g * 64; bb < g * 64 + 64; ++bb) {
    float2 v = *(const float2*)&pstatB[(size_t)bb * 512 + t * 2];
    s += v.x; s2 += v.y;
  }
  *(float2*)&p2[(size_t)g * 512 + t * 2] = make_float2(s, s2);
}

// ---- per-o BN stage B: fold 32 partials (64KB, L2) -> scl = g*rsqrt(var+eps) ----
__global__ void k_stats_o_finB(const float* __restrict__ p2,
                               const float* __restrict__ g, float* __restrict__ scl) {
  const int o = threadIdx.x;   // 256 threads, 1 block
  float s = 0.f, s2 = 0.f;
#pragma unroll
  for (int p = 0; p < 32; ++p) {
    float2 v = *(const float2*)&p2[(size_t)p * 512 + o * 2];
    s += v.x; s2 += v.y;
  }
  float invN = 1.0f / (float)(NB * 64);
  float m = s * invN;
  float var = s2 * invN - m * m;
  scl[o] = g[o] * rsqrtf(var + 1e-5f);
}

// ---- pipelined bf16 GEMM, C[m][n] = sum_k A[m][k]*B[n][k] (B^T layout), split-K ----
// BM=BN=128, BK=32, 4 waves (2x2), ring-4 LDS slots (64KB) as 2 ping-pong PAIRS
// (32 MFMA per sync-pair) + chunk-XOR bank swizzle (conflicts measured 0).
__global__ __launch_bounds__(256) void k_gemmp(const u16* __restrict__ A,
                                               const u16* __restrict__ B,
                                               float* __restrict__ C,
                                               int M, int N, int K, int ksz) {
  __shared__ u16 lds[4 * 8192];   // 4 slots x 16KB = 64KB
  const int tid = threadIdx.x, lane = tid & 63, wid = tid >> 6;
  const int wr = wid >> 1, wc = wid & 1;

  const int nx = gridDim.x, ny = gridDim.y;
  const int nwg = nx * ny * gridDim.z;
  int lin = blockIdx.x + nx * (blockIdx.y + ny * blockIdx.z);
  int swz = (lin & 7) * (nwg >> 3) + (lin >> 3);   // nwg % 8 == 0
  const int bx = swz % nx;
  const int byz = swz / nx;
  const int by = byz % ny, bz = byz / ny;

  const int m0 = bx * 128, n0 = by * 128;
  const int k0 = bz * ksz;
  C += (size_t)bz * ((size_t)M * N);

  f32x4 acc[4][4];
#pragma unroll
  for (int mi = 0; mi < 4; ++mi)
#pragma unroll
    for (int ni = 0; ni < 4; ++ni) acc[mi][ni] = (f32x4){0.f, 0.f, 0.f, 0.f};

  const int gchunk = (lane & 3) ^ ((lane >> 3) & 3);
  const u16* gstage = (wid < 2)
      ? A + (size_t)(m0 + wid * 64 + (lane >> 2)) * K + k0 + gchunk * 8
      : B + (size_t)(n0 + (wid - 2) * 64 + (lane >> 2)) * K + k0 + gchunk * 8;
  const int lstage = (wid < 2) ? (wid * 64) * 32 : 4096 + ((wid - 2) * 64) * 32;

  const int la15 = lane & 15, la4 = lane >> 4;
  int aoffs[4], boffs[4];
#pragma unroll
  for (int i = 0; i < 4; ++i) {
    int ra = wr * 64 + i * 16 + la15;
    aoffs[i] = ra * 32 + ((la4 ^ ((ra >> 1) & 3)) * 8);
    int rb = wc * 64 + i * 16 + la15;
    boffs[i] = 4096 + rb * 32 + ((la4 ^ ((rb >> 1) & 3)) * 8);
  }

  const int nkt = ksz / 32;
#pragma unroll
  for (int t = 0; t < 4; ++t)
#pragma unroll
    for (int i = 0; i < 4; ++i)
      GLOAD16(gstage + (size_t)t * 32 + (size_t)i * 16 * K, lds + t * 8192 + lstage + i * 512);
  asm volatile("s_waitcnt vmcnt(8)" ::: "memory");   // tiles 0,1 (mine) landed
  __builtin_amdgcn_sched_barrier(0);
  __builtin_amdgcn_s_barrier();                      // tiles 0,1 (everyone's) landed
  __builtin_amdgcn_sched_barrier(0);

  int pbase = 0;   // 0 -> slots {0,1}, 16384 -> slots {2,3}
  for (int jj = 0; jj < nkt; jj += 2) {
    const int sa = pbase, sb = pbase + 8192;
    bf16x8 af0[4], bf0[4], af1[4], bf1[4];
#pragma unroll
    for (int i = 0; i < 4; ++i) {
      af0[i] = *(const bf16x8*)(lds + sa + aoffs[i]);
      bf0[i] = *(const bf16x8*)(lds + sa + boffs[i]);
      af1[i] = *(const bf16x8*)(lds + sb + aoffs[i]);
      bf1[i] = *(const bf16x8*)(lds + sb + boffs[i]);
    }
    asm volatile("s_waitcnt lgkmcnt(0)" ::: "memory");  // my reads of both slots done
    __builtin_amdgcn_sched_barrier(0);
    __builtin_amdgcn_s_barrier();                       // all waves' reads done
    __builtin_amdgcn_sched_barrier(0);
    const int ts0 = (jj + 4 < nkt) ? jj + 4 : nkt - 1;  // tail: benign dummy re-stage
    const int ts1 = (jj + 5 < nkt) ? jj + 5 : nkt - 1;
#pragma unroll
    for (int i = 0; i < 4; ++i)
      GLOAD16(gstage + (size_t)ts0 * 32 + (size_t)i * 16 * K, lds + sa + lstage + i * 512);
#pragma unroll
    for (int i = 0; i < 4; ++i)
      GLOAD16(gstage + (size_t)ts1 * 32 + (size_t)i * 16 * K, lds + sb + lstage + i * 512);
    __builtin_amdgcn_s_setprio(1);
#pragma unroll
    for (int mi = 0; mi < 4; ++mi)
#pragma unroll
      for (int ni = 0; ni < 4; ++ni)
        acc[mi][ni] = __builtin_amdgcn_mfma_f32_16x16x32_bf16(af0[mi], bf0[ni], acc[mi][ni], 0, 0, 0);
#pragma unroll
    for (int mi = 0; mi < 4; ++mi)
#pragma unroll
      for (int ni = 0; ni < 4; ++ni)
        acc[mi][ni] = __builtin_amdgcn_mfma_f32_16x16x32_bf16(af1[mi], bf1[ni], acc[mi][ni], 0, 0, 0);
    __builtin_amdgcn_s_setprio(0);
    asm volatile("s_waitcnt vmcnt(8)" ::: "memory");    // tiles jj+2,jj+3 (mine) landed
    __builtin_amdgcn_sched_barrier(0);
    __builtin_amdgcn_s_barrier();                       // (everyone's) landed
    __builtin_amdgcn_sched_barrier(0);
    pbase ^= 16384;
  }

#pragma unroll
  for (int mi = 0; mi < 4; ++mi) {
    int m = m0 + wr * 64 + mi * 16 + ((lane >> 4) * 4);
#pragma unroll
    for (int ni = 0; ni < 4; ++ni) {
      int n = n0 + wc * 64 + ni * 16 + (lane & 15);
#pragma unroll
      for (int i = 0; i < 4; ++i) C[(size_t)(m + i) * N + n] = acc[mi][ni][i];
    }
  }
}

// ---- fused: r = sum of NP split-K partials  +  per-(rowgroup,col) BN partial stats ----
template <int NP>
__global__ void k_red_stats(const float* __restrict__ c, float* __restrict__ r,
                            float* __restrict__ pstat) {
  const int col = blockIdx.x * 64 + (threadIdx.x & 63);
  const int rt = threadIdx.x >> 6;
  const int rg = blockIdx.y;
  const size_t ps = (size_t)NB * 1024;
  float s = 0.f, s2 = 0.f;
  for (int rr = rt; rr < 64; rr += 4) {
    size_t idx = (size_t)(rg * 64 + rr) * 1024 + col;
    float v = c[idx];
#pragma unroll
    for (int p = 1; p < NP; ++p) v += c[p * ps + idx];
    r[idx] = v;
    s += v;
    s2 = fmaf(v, v, s2);
  }
  __shared__ float red[2][256];
  red[0][threadIdx.x] = s; red[1][threadIdx.x] = s2;
  __syncthreads();
  if (threadIdx.x < 64) {
    int t = threadIdx.x;
    s  = red[0][t] + red[0][t + 64] + red[0][t + 128] + red[0][t + 192];
    s2 = red[1][t] + red[1][t + 64] + red[1][t + 128] + red[1][t + 192];
    pstat[((size_t)rg * 1024 + col) * 2]     = s;
    pstat[((size_t)rg * 1024 + col) * 2 + 1] = s2;
  }
}

// ---- finalize col BN: fold 32 rowgroup partials -> scl/bia ----
__global__ void k_stats_fin(const float* __restrict__ pstat,
                            const float* __restrict__ g, const float* __restrict__ be,
                            float* __restrict__ scl, float* __restrict__ bia) {
  int col = blockIdx.x * 256 + threadIdx.x;
  float s = 0.f, s2 = 0.f;
#pragma unroll
  for (int p = 0; p < 32; ++p) {
    s  += pstat[((size_t)p * 1024 + col) * 2];
    s2 += pstat[((size_t)p * 1024 + col) * 2 + 1];
  }
  float invN = 1.0f / (float)NB;
  float m = s * invN;
  float var = s2 * invN - m * m;
  float inv = rsqrtf(var + 1e-5f);
  scl[col] = g[col] * inv;
  bia[col] = be[col] - g[col] * inv * m;
}

// ---------------- a1 = bf16(relu(r0*scl + bia)) ----------------
__global__ void k_applyA1(const float* __restrict__ c0,
                          const float* __restrict__ scl, const float* __restrict__ bia,
                          u16* __restrict__ a1) {
  size_t i4 = ((size_t)blockIdx.x * 256 + threadIdx.x) * 4;
  int n = (int)(i4 & 1023);
  float4 v0 = *(const float4*)(c0 + i4);
  ushort4 o;
  o.x = f2bf(fmaxf(fmaf(v0.x, scl[n + 0], bia[n + 0]), 0.f));
  o.y = f2bf(fmaxf(fmaf(v0.y, scl[n + 1], bia[n + 1]), 0.f));
  o.z = f2bf(fmaxf(fmaf(v0.z, scl[n + 2], bia[n + 2]), 0.f));
  o.w = f2bf(fmaxf(fmaf(v0.w, scl[n + 3], bia[n + 3]), 0.f));
  *(ushort4*)(a1 + i4) = o;
}

// -------- y[b] = out_b + sum_n relu(h*scl+bia)*out_w[n] --------
__global__ void k_final(const float* __restrict__ h, const float* __restrict__ scl,
                        const float* __restrict__ bia, const float* __restrict__ ow,
                        const float* __restrict__ ob, float* __restrict__ y) {
  int lane = threadIdx.x & 63, wid = threadIdx.x >> 6;
  int row = blockIdx.x * 4 + wid;
  const float* hr = h + (size_t)row * 1024;
  float part = 0.f;
#pragma unroll
  for (int j = 0; j < 16; ++j) {
    int n = j * 64 + lane;
    float v = fmaxf(fmaf(hr[n], scl[n], bia[n]), 0.f);
    part = fmaf(v, ow[n], part);
  }
#pragma unroll
  for (int off = 32; off >= 1; off >>= 1) part += __shfl_xor(part, off);
  if (lane == 0) y[row] = part + ob[0];
}

extern "C" void kernel_launch(void* const* d_in, const int* in_sizes, int n_in,
                              void* d_out, int out_size, void* d_ws, size_t ws_size,
                              hipStream_t stream) {
  const int*   ids   = (const int*)d_in[0];
  const float* vals  = (const float*)d_in[1];
  const float* etab  = (const float*)d_in[2];
  const float* wb    = (const float*)d_in[3];
  const float* query = (const float*)d_in[4];
  const float* att   = (const float*)d_in[5];
  const float* bng   = (const float*)d_in[6];
  const float* w0    = (const float*)d_in[8];
  const float* g0    = (const float*)d_in[10];
  const float* be0   = (const float*)d_in[11];
  const float* w1    = (const float*)d_in[12];
  const float* g1    = (const float*)d_in[14];
  const float* be1   = (const float*)d_in[15];
  const float* outw  = (const float*)d_in[16];
  const float* outb  = (const float*)d_in[17];
  float* y = (float*)d_out;

  // workspace layout (peak ~195.6 MB):
  //   [0, 32K)            mt
  //   [32K, 33.59M)       w0bf (32MB, pre-scaled by arm-BN scl)
  //   [33.59M, 35.68M)    w1bf (2MB)
  //   [35.68M, 102.79M)   tbuf (64MB bf16)  -- alive through gemm0 (A operand)
  //   [102.79M, 136.35M)  c01 (4x8MB f32)   -- gemm0 partials; dead after red_stats<4>
  //   [102.79M, 136.35M)  h1 (4x8MB f32)    -- overlays dead c01; gemm1 partials
  //   [136.35M, +64K)     pstatB2 (stage-A o-stats)
  //   [169.90M, 178.29M)  r0 (8MB f32)
  //   [178.29M, 182.48M)  a1 (4MB bf16)
  //   [182.48M, 186.68M)  pstatB (4MB, per-block o-stats)
  //   [186.68M, 195.07M)  h (8MB f32, summed)
  //   [195.07M, ...)      pstat1/pstat2 + BN scalars
  char* ws = (char*)d_ws;
  u16*   mt     = (u16*)(ws + 0);
  u16*   w0bf   = (u16*)(ws + 32768ull);
  u16*   w1bf   = (u16*)(ws + 33587200ull);
  u16*   tbuf   = (u16*)(ws + 35684352ull);
  float* c01    = (float*)(ws + 102793216ull);
  float* h1     = (float*)(ws + 102793216ull);
  float* pstatB2= (float*)(ws + 136347648ull);
  float* r0     = (float*)(ws + 169902080ull);
  u16*   a1     = (u16*)(ws + 178290688ull);
  float* pstatB = (float*)(ws + 182484992ull);
  float* h      = (float*)(ws + 186679296ull);
  float* pstat1 = (float*)(ws + 195067904ull);
  float* pstat2 = (float*)(ws + 195330048ull);
  float* sclA   = (float*)(ws + 195608576ull);
  float* scl1   = (float*)(ws + 195609600ull);
  float* bia1   = (float*)(ws + 195613696ull);
  float* scl2   = (float*)(ws + 195617792ull);
  float* bia2   = (float*)(ws + 195621888ull);

  k_prep<<<1088, 256, 0, stream>>>(wb, query, mt, w1, w1bf);
  k_mega<<<2048, 256, 0, stream>>>(ids, vals, etab, mt, att, tbuf, pstatB);
  k_stats_oA<<<32, 256, 0, stream>>>(pstatB, pstatB2);
  k_stats_o_finB<<<1, 256, 0, stream>>>(pstatB2, bng, sclA);
  k_cvt_w0s<<<16384, 256, 0, stream>>>(w0, sclA, w0bf);
  // gemm0: ring-4 (64KB, 2/CU), 2-tile-per-sync, split-K=4 -> 512 blocks, ksz=4096 (nkt=128)
  k_gemmp<<<dim3(16, 8, 4), 256, 0, stream>>>(tbuf, w0bf, c01, 2048, 1024, 16384, 4096);
  k_red_stats<4><<<dim3(16, 32), 256, 0, stream>>>(c01, r0, pstat1);
  k_stats_fin<<<4, 256, 0, stream>>>(pstat1, g0, be0, scl1, bia1);
  k_applyA1<<<2048, 256, 0, stream>>>(r0, scl1, bia1, a1);
  // gemm1: same kernel, split-K=4 -> 512 blocks, ksz=256 (nkt=8)
  k_gemmp<<<dim3(16, 8, 4), 256, 0, stream>>>(a1, w1bf, h1, 2048, 1024, 1024, 256);
  k_red_stats<4><<<dim3(16, 32), 256, 0, stream>>>(h1, h, pstat2);
  k_stats_fin<<<4, 256, 0, stream>>>(pstat2, g1, be1, scl2, bia2);
  k_final<<<512, 256, 0, stream>>>(h, scl2, bia2, outw, outb, y);
}

// Round 18
// 240.343 us; speedup vs baseline: 1.2419x; 1.0235x over previous
//
#include <hip/hip_runtime.h>

typedef unsigned short u16;
typedef __attribute__((ext_vector_type(8))) short bf16x8;
typedef __attribute__((ext_vector_type(8))) unsigned short u16x8;
typedef __attribute__((ext_vector_type(4))) float f32x4;

__device__ __forceinline__ u16 f2bf(float f) {
  unsigned u = __builtin_bit_cast(unsigned, f);
  u += 0x7fffu + ((u >> 16) & 1u);
  return (u16)(u >> 16);
}
__device__ __forceinline__ float bf2f(u16 h) {
  unsigned u = ((unsigned)h) << 16;
  return __builtin_bit_cast(float, u);
}

#define NB 2048
#define NF 100
#define NE 64
#define NO 256
#define OCH 64
#define EMB_ST 72
#define EMBT_ST 136
#define GAW_ST 136

#define GLOAD16(gsrc, ldst)                                                        \
  __builtin_amdgcn_global_load_lds(                                                \
      (const __attribute__((address_space(1))) unsigned int*)(gsrc),               \
      (__attribute__((address_space(3))) unsigned int*)(ldst), 16, 0, 0)

// ---- prep (merged): blocks 0..63 compute M = (query·Wb)*0.0625; rest cvt w1 ----
__global__ void k_prep(const float* __restrict__ wb, const float* __restrict__ q,
                       u16* __restrict__ mt, const float* __restrict__ w1,
                       u16* __restrict__ w1bf) {
  if (blockIdx.x < 64) {
    int idx = blockIdx.x * 256 + threadIdx.x;   // 16384 = 256*64
    int o = idx >> 6, e = idx & 63;
    float s = 0.f;
    for (int k = 0; k < 64; ++k) s = fmaf(q[o * 64 + k], wb[k * 64 + e], s);
    mt[idx] = f2bf(s * 0.0625f);   // folds DK^-0.5 (0.125) and (alpha-1) (0.5)
  } else {
    int i4 = ((blockIdx.x - 64) * 256 + threadIdx.x) * 4;
    float4 v = *(const float4*)(w1 + i4);
    ushort4 o;
    o.x = f2bf(v.x); o.y = f2bf(v.y); o.z = f2bf(v.z); o.w = f2bf(v.w);
    *(ushort4*)(w1bf + i4) = o;
  }
}

// ------- f32 -> bf16 with per-k scale: w0'[n][k] = bf16(w0[n][k] * scl[k>>6]) -------
__global__ void k_cvt_w0s(const float* __restrict__ in, const float* __restrict__ scl,
                          u16* __restrict__ out) {
  size_t i4 = ((size_t)blockIdx.x * 256 + threadIdx.x) * 4;
  int o = (int)((i4 >> 6) & 255);
  float sc = scl[o];
  float4 v = *(const float4*)(in + i4);
  ushort4 u;
  u.x = f2bf(v.x * sc); u.y = f2bf(v.y * sc);
  u.z = f2bf(v.z * sc); u.w = f2bf(v.w * sc);
  *(ushort4*)(out + i4) = u;
}

// ------- fused gather + (per-o-chunk: gates GEMM + entmax + arm GEMM + exp-1) -------
// Wave-local phases (R13): each wave owns its 16 o-rows end-to-end; 2 barriers total.
__global__ __launch_bounds__(256) void k_mega(
    const int* __restrict__ ids, const float* __restrict__ vals,
    const float* __restrict__ etab, const u16* __restrict__ mt,
    const float* __restrict__ att, u16* __restrict__ tbuf,
    float* __restrict__ pstatB) {
  __shared__ u16 s_emb[112][EMB_ST];     // [f][e], rows 100..111 zero
  __shared__ u16 s_embT[64][EMBT_ST];    // [e][f], cols 100..135 zero
  __shared__ u16 s_gaw[64][GAW_ST];      // gates, then p*att (wave-local rows)
  __shared__ float s_rs[64];             // per-row 1/sum(p) (wave-local)
  __shared__ float s_ps[256][2];         // per-o {sum, sumsq} over e for this b

  const int tid = threadIdx.x;
  const int lane = tid & 63;
  const int wid = tid >> 6;
  const int b = blockIdx.x;

  // phase 0: gather emb = emb_table[ids]*clip(v)  (once per b; cross-wave)
  for (int f = wid; f < NF; f += 4) {
    int id = ids[b * NF + f];
    float v = vals[b * NF + f];
    v = fminf(fmaxf(v, 0.001f), 1.0f);
    float ev = etab[(size_t)id * NE + lane] * v;
    u16 bf = f2bf(ev);
    s_emb[f][lane] = bf;
    s_embT[lane][f] = bf;
  }
  for (int i = tid; i < 12 * EMB_ST; i += 256) s_emb[100 + i / EMB_ST][i % EMB_ST] = 0;
  for (int i = tid; i < 64 * 36; i += 256) s_embT[i / 36][100 + i % 36] = 0;
  for (int i = tid; i < 64 * 24; i += 256) s_gaw[i / 24][112 + i % 24] = 0;
  __syncthreads();   // s_emb/s_embT/s_gaw-pad visible to all waves (read-only after)

  for (int oc = 0; oc < 4; ++oc) {
    const int obase = oc * OCH;
    bf16x8 amt[2];
#pragma unroll
    for (int kh = 0; kh < 2; ++kh)
      amt[kh] = *(const bf16x8*)(mt + ((obase + wid * 16 + (lane & 15)) * 64 +
                                       kh * 32 + ((lane >> 4) * 8)));

    // phase 1: gates[o][f] = M[o,:]·emb[f,:]  (writes wave-local s_gaw rows)
#pragma unroll
    for (int ft = 0; ft < 7; ++ft) {
      f32x4 acc = {0.f, 0.f, 0.f, 0.f};
#pragma unroll
      for (int kh = 0; kh < 2; ++kh) {
        bf16x8 bfr = *(const bf16x8*)&s_emb[ft * 16 + (lane & 15)][kh * 32 + ((lane >> 4) * 8)];
        acc = __builtin_amdgcn_mfma_f32_16x16x32_bf16(amt[kh], bfr, acc, 0, 0, 0);
      }
      int fc = ft * 16 + (lane & 15);
      if (fc < NF) {
#pragma unroll
        for (int i = 0; i < 4; ++i)
          s_gaw[wid * 16 + ((lane >> 4) * 4) + i][fc] = f2bf(acc[i]);
      }
    }
    asm volatile("" ::: "memory");   // pin phase-1 writes before phase-2 reads (same wave)

    // phase 2: entmax(alpha=1.5), Newton x3 + rcp; quad per o-row, WAVE-LOCAL rows.
    // Residual tau error after 3 iters is common-mode per row; the final
    // normalization cancels it exactly in the (slowest-converging) near-uniform
    // case and to first order otherwise. absmax has been invariant across
    // 22-bisect -> Newton-5 -> Newton-4 (downstream bf16 rounding dominates).
    {
      const int q = lane & 3;
      const int rl = lane >> 2;            // 0..15 within wave's slice
      const int r = wid * 16 + rl;         // s_gaw/s_rs row (this wave's)
      const int og = obase + r;
      float x[28];
#pragma unroll
      for (int j = 0; j < 7; ++j) {
        ushort4 g = *(const ushort4*)&s_gaw[r][j * 16 + q * 4];
        x[j * 4 + 0] = bf2f(g.x); x[j * 4 + 1] = bf2f(g.y);
        x[j * 4 + 2] = bf2f(g.z); x[j * 4 + 3] = bf2f(g.w);
      }
      if (q > 0) { x[24] = -1e30f; x[25] = -1e30f; x[26] = -1e30f; x[27] = -1e30f; }
      float attv[28];
#pragma unroll
      for (int j = 0; j < 7; ++j) {
        if (j < 6 || q == 0) {
          float4 av = *(const float4*)(att + og * NF + j * 16 + q * 4);
          attv[j * 4 + 0] = av.x; attv[j * 4 + 1] = av.y;
          attv[j * 4 + 2] = av.z; attv[j * 4 + 3] = av.w;
        } else {
          attv[j * 4 + 0] = 0.f; attv[j * 4 + 1] = 0.f;
          attv[j * 4 + 2] = 0.f; attv[j * 4 + 3] = 0.f;
        }
      }
      float m0 = x[0], m1 = x[1];
#pragma unroll
      for (int j = 2; j < 28; j += 2) { m0 = fmaxf(m0, x[j]); m1 = fmaxf(m1, x[j + 1]); }
      float mx = fmaxf(m0, m1);
      mx = fmaxf(mx, __shfl_xor(mx, 1));
      mx = fmaxf(mx, __shfl_xor(mx, 2));
      float tau = mx - 1.0f;
#pragma unroll
      for (int it = 0; it < 3; ++it) {
        float s0 = 0.f, s1 = 0.f, t0 = 0.f, t1 = 0.f;
#pragma unroll
        for (int j = 0; j < 14; ++j) {
          float d0 = fmaxf(x[j] - tau, 0.f);
          float d1 = fmaxf(x[j + 14] - tau, 0.f);
          s0 = fmaf(d0, d0, s0); s1 = fmaf(d1, d1, s1);
          t0 += d0; t1 += d1;
        }
        float s = s0 + s1, sd = t0 + t1;
        s += __shfl_xor(s, 1);
        s += __shfl_xor(s, 2);
        sd += __shfl_xor(sd, 1);
        sd += __shfl_xor(sd, 2);
        float den = 2.0f * sd + 1e-30f;
        float inv;
        asm("v_rcp_f32 %0, %1" : "=v"(inv) : "v"(den));
        tau += (s - 1.0f) * inv;
      }
      float s0 = 0.f, s1 = 0.f;
#pragma unroll
      for (int j = 0; j < 14; ++j) {
        float d0 = fmaxf(x[j] - tau, 0.f);
        float d1 = fmaxf(x[j + 14] - tau, 0.f);
        x[j] = d0 * d0;
        x[j + 14] = d1 * d1;
        s0 += x[j]; s1 += x[j + 14];
      }
      float s = s0 + s1;
      s += __shfl_xor(s, 1);
      s += __shfl_xor(s, 2);
      if (q == 0) s_rs[r] = 1.0f / s;
#pragma unroll
      for (int j = 0; j < 7; ++j) {
        ushort4 w;
        w.x = f2bf(x[j * 4 + 0] * attv[j * 4 + 0]);
        w.y = f2bf(x[j * 4 + 1] * attv[j * 4 + 1]);
        w.z = f2bf(x[j * 4 + 2] * attv[j * 4 + 2]);
        w.w = f2bf(x[j * 4 + 3] * attv[j * 4 + 3]);
        *(ushort4*)&s_gaw[r][j * 16 + q * 4] = w;
      }
    }
    asm volatile("" ::: "memory");   // pin phase-2 writes before phase-3 reads (same wave)

    // phase 3: arm[o][e] = rs[o] * sum_f aw[o][f]*emb[f][e];  t = exp(arm)-1
    f32x4 acc[4] = {};
#pragma unroll
    for (int h = 0; h < 4; ++h) {
      bf16x8 afr = *(const bf16x8*)&s_gaw[wid * 16 + (lane & 15)][h * 32 + ((lane >> 4) * 8)];
#pragma unroll
      for (int et = 0; et < 4; ++et) {
        bf16x8 bfr = *(const bf16x8*)&s_embT[et * 16 + (lane & 15)][h * 32 + ((lane >> 4) * 8)];
        acc[et] = __builtin_amdgcn_mfma_f32_16x16x32_bf16(afr, bfr, acc[et], 0, 0, 0);
      }
    }
    const int rloc = wid * 16 + ((lane >> 4) * 4);
    float rs4[4];
#pragma unroll
    for (int i = 0; i < 4; ++i) rs4[i] = s_rs[rloc + i];
    float tval[4][4];   // [et][i]
#pragma unroll
    for (int et = 0; et < 4; ++et)
#pragma unroll
      for (int i = 0; i < 4; ++i)
        tval[et][i] = __expf(acc[et][i] * rs4[i]) - 1.0f;
    size_t orow = (size_t)b * NO + obase + rloc;
#pragma unroll
    for (int et = 0; et < 4; ++et) {
      int e = et * 16 + (lane & 15);
#pragma unroll
      for (int i = 0; i < 4; ++i)
        tbuf[(orow + i) * 64 + e] = f2bf(tval[et][i]);
    }
    // fused BN partials: per row, sum over e (4 et cols here x 16 lanes of group)
#pragma unroll
    for (int i = 0; i < 4; ++i) {
      float sp = tval[0][i] + tval[1][i] + tval[2][i] + tval[3][i];
      float sq = fmaf(tval[0][i], tval[0][i],
                 fmaf(tval[1][i], tval[1][i],
                 fmaf(tval[2][i], tval[2][i], tval[3][i] * tval[3][i])));
#pragma unroll
      for (int m = 1; m < 16; m <<= 1) {
        sp += __shfl_xor(sp, m);
        sq += __shfl_xor(sq, m);
      }
      if ((lane & 15) == 0) {
        s_ps[obase + rloc + i][0] = sp;
        s_ps[obase + rloc + i][1] = sq;
      }
    }
    asm volatile("" ::: "memory");   // pin phase-3 reads before next-oc phase-1 writes
  }
  __syncthreads();   // s_ps is read cross-wave below
  // write per-block BN partials (coalesced: 256 threads x float2)
  *(float2*)&pstatB[(size_t)b * 512 + tid * 2] =
      make_float2(s_ps[tid][0], s_ps[tid][1]);
}

// ---- per-o BN stage A: sum 64 bb-rows of pstatB, fully coalesced ----
__global__ void k_stats_oA(const float* __restrict__ pstatB, float* __restrict__ p2) {
  const int g = blockIdx.x, t = threadIdx.x;
  float s = 0.f, s2 = 0.f;
  for (int bb = g * 64; bb < g * 64 + 64; ++bb) {
    float2 v = *(const float2*)&pstatB[(size_t)bb * 512 + t * 2];
    s += v.x; s2 += v.y;
  }
  *(float2*)&p2[(size_t)g * 512 + t * 2] = make_float2(s, s2);
}

// ---- per-o BN stage B: fold 32 partials (64KB, L2) -> scl = g*rsqrt(var+eps) ----
__global__ void k_stats_o_finB(const float* __restrict__ p2,
                               const float* __restrict__ g, float* __restrict__ scl) {
  const int o = threadIdx.x;   // 256 threads, 1 block
  float s = 0.f, s2 = 0.f;
#pragma unroll
  for (int p = 0; p < 32; ++p) {
    float2 v = *(const float2*)&p2[(size_t)p * 512 + o * 2];
    s += v.x; s2 += v.y;
  }
  float invN = 1.0f / (float)(NB * 64);
  float m = s * invN;
  float var = s2 * invN - m * m;
  scl[o] = g[o] * rsqrtf(var + 1e-5f);
}

// ---- pipelined bf16 GEMM, C[m][n] = sum_k A[m][k]*B[n][k] (B^T layout), split-K ----
// BM=BN=128, BK=32, 4 waves (2x2), ring-4 LDS slots (64KB) as 2 ping-pong PAIRS
// (32 MFMA per sync-pair) + chunk-XOR bank swizzle (conflicts measured 0).
__global__ __launch_bounds__(256) void k_gemmp(const u16* __restrict__ A,
                                               const u16* __restrict__ B,
                                               float* __restrict__ C,
                                               int M, int N, int K, int ksz) {
  __shared__ u16 lds[4 * 8192];   // 4 slots x 16KB = 64KB
  const int tid = threadIdx.x, lane = tid & 63, wid = tid >> 6;
  const int wr = wid >> 1, wc = wid & 1;

  const int nx = gridDim.x, ny = gridDim.y;
  const int nwg = nx * ny * gridDim.z;
  int lin = blockIdx.x + nx * (blockIdx.y + ny * blockIdx.z);
  int swz = (lin & 7) * (nwg >> 3) + (lin >> 3);   // nwg % 8 == 0
  const int bx = swz % nx;
  const int byz = swz / nx;
  const int by = byz % ny, bz = byz / ny;

  const int m0 = bx * 128, n0 = by * 128;
  const int k0 = bz * ksz;
  C += (size_t)bz * ((size_t)M * N);

  f32x4 acc[4][4];
#pragma unroll
  for (int mi = 0; mi < 4; ++mi)
#pragma unroll
    for (int ni = 0; ni < 4; ++ni) acc[mi][ni] = (f32x4){0.f, 0.f, 0.f, 0.f};

  const int gchunk = (lane & 3) ^ ((lane >> 3) & 3);
  const u16* gstage = (wid < 2)
      ? A + (size_t)(m0 + wid * 64 + (lane >> 2)) * K + k0 + gchunk * 8
      : B + (size_t)(n0 + (wid - 2) * 64 + (lane >> 2)) * K + k0 + gchunk * 8;
  const int lstage = (wid < 2) ? (wid * 64) * 32 : 4096 + ((wid - 2) * 64) * 32;

  const int la15 = lane & 15, la4 = lane >> 4;
  int aoffs[4], boffs[4];
#pragma unroll
  for (int i = 0; i < 4; ++i) {
    int ra = wr * 64 + i * 16 + la15;
    aoffs[i] = ra * 32 + ((la4 ^ ((ra >> 1) & 3)) * 8);
    int rb = wc * 64 + i * 16 + la15;
    boffs[i] = 4096 + rb * 32 + ((la4 ^ ((rb >> 1) & 3)) * 8);
  }

  const int nkt = ksz / 32;
#pragma unroll
  for (int t = 0; t < 4; ++t)
#pragma unroll
    for (int i = 0; i < 4; ++i)
      GLOAD16(gstage + (size_t)t * 32 + (size_t)i * 16 * K, lds + t * 8192 + lstage + i * 512);
  asm volatile("s_waitcnt vmcnt(8)" ::: "memory");   // tiles 0,1 (mine) landed
  __builtin_amdgcn_sched_barrier(0);
  __builtin_amdgcn_s_barrier();                      // tiles 0,1 (everyone's) landed
  __builtin_amdgcn_sched_barrier(0);

  int pbase = 0;   // 0 -> slots {0,1}, 16384 -> slots {2,3}
  for (int jj = 0; jj < nkt; jj += 2) {
    const int sa = pbase, sb = pbase + 8192;
    bf16x8 af0[4], bf0[4], af1[4], bf1[4];
#pragma unroll
    for (int i = 0; i < 4; ++i) {
      af0[i] = *(const bf16x8*)(lds + sa + aoffs[i]);
      bf0[i] = *(const bf16x8*)(lds + sa + boffs[i]);
      af1[i] = *(const bf16x8*)(lds + sb + aoffs[i]);
      bf1[i] = *(const bf16x8*)(lds + sb + boffs[i]);
    }
    asm volatile("s_waitcnt lgkmcnt(0)" ::: "memory");  // my reads of both slots done
    __builtin_amdgcn_sched_barrier(0);
    __builtin_amdgcn_s_barrier();                       // all waves' reads done
    __builtin_amdgcn_sched_barrier(0);
    const int ts0 = (jj + 4 < nkt) ? jj + 4 : nkt - 1;  // tail: benign dummy re-stage
    const int ts1 = (jj + 5 < nkt) ? jj + 5 : nkt - 1;
#pragma unroll
    for (int i = 0; i < 4; ++i)
      GLOAD16(gstage + (size_t)ts0 * 32 + (size_t)i * 16 * K, lds + sa + lstage + i * 512);
#pragma unroll
    for (int i = 0; i < 4; ++i)
      GLOAD16(gstage + (size_t)ts1 * 32 + (size_t)i * 16 * K, lds + sb + lstage + i * 512);
    __builtin_amdgcn_s_setprio(1);
#pragma unroll
    for (int mi = 0; mi < 4; ++mi)
#pragma unroll
      for (int ni = 0; ni < 4; ++ni)
        acc[mi][ni] = __builtin_amdgcn_mfma_f32_16x16x32_bf16(af0[mi], bf0[ni], acc[mi][ni], 0, 0, 0);
#pragma unroll
    for (int mi = 0; mi < 4; ++mi)
#pragma unroll
      for (int ni = 0; ni < 4; ++ni)
        acc[mi][ni] = __builtin_amdgcn_mfma_f32_16x16x32_bf16(af1[mi], bf1[ni], acc[mi][ni], 0, 0, 0);
    __builtin_amdgcn_s_setprio(0);
    asm volatile("s_waitcnt vmcnt(8)" ::: "memory");    // tiles jj+2,jj+3 (mine) landed
    __builtin_amdgcn_sched_barrier(0);
    __builtin_amdgcn_s_barrier();                       // (everyone's) landed
    __builtin_amdgcn_sched_barrier(0);
    pbase ^= 16384;
  }

#pragma unroll
  for (int mi = 0; mi < 4; ++mi) {
    int m = m0 + wr * 64 + mi * 16 + ((lane >> 4) * 4);
#pragma unroll
    for (int ni = 0; ni < 4; ++ni) {
      int n = n0 + wc * 64 + ni * 16 + (lane & 15);
#pragma unroll
      for (int i = 0; i < 4; ++i) C[(size_t)(m + i) * N + n] = acc[mi][ni][i];
    }
  }
}

// ---- fused: r = sum of NP split-K partials  +  per-(rowgroup,col) BN partial stats ----
template <int NP>
__global__ void k_red_stats(const float* __restrict__ c, float* __restrict__ r,
                            float* __restrict__ pstat) {
  const int col = blockIdx.x * 64 + (threadIdx.x & 63);
  const int rt = threadIdx.x >> 6;
  const int rg = blockIdx.y;
  const size_t ps = (size_t)NB * 1024;
  float s = 0.f, s2 = 0.f;
  for (int rr = rt; rr < 64; rr += 4) {
    size_t idx = (size_t)(rg * 64 + rr) * 1024 + col;
    float v = c[idx];
#pragma unroll
    for (int p = 1; p < NP; ++p) v += c[p * ps + idx];
    r[idx] = v;
    s += v;
    s2 = fmaf(v, v, s2);
  }
  __shared__ float red[2][256];
  red[0][threadIdx.x] = s; red[1][threadIdx.x] = s2;
  __syncthreads();
  if (threadIdx.x < 64) {
    int t = threadIdx.x;
    s  = red[0][t] + red[0][t + 64] + red[0][t + 128] + red[0][t + 192];
    s2 = red[1][t] + red[1][t + 64] + red[1][t + 128] + red[1][t + 192];
    pstat[((size_t)rg * 1024 + col) * 2]     = s;
    pstat[((size_t)rg * 1024 + col) * 2 + 1] = s2;
  }
}

// ---- finalize col BN: fold 32 rowgroup partials -> scl/bia ----
__global__ void k_stats_fin(const float* __restrict__ pstat,
                            const float* __restrict__ g, const float* __restrict__ be,
                            float* __restrict__ scl, float* __restrict__ bia) {
  int col = blockIdx.x * 256 + threadIdx.x;
  float s = 0.f, s2 = 0.f;
#pragma unroll
  for (int p = 0; p < 32; ++p) {
    s  += pstat[((size_t)p * 1024 + col) * 2];
    s2 += pstat[((size_t)p * 1024 + col) * 2 + 1];
  }
  float invN = 1.0f / (float)NB;
  float m = s * invN;
  float var = s2 * invN - m * m;
  float inv = rsqrtf(var + 1e-5f);
  scl[col] = g[col] * inv;
  bia[col] = be[col] - g[col] * inv * m;
}

// ---------------- a1 = bf16(relu(r0*scl + bia)) ----------------
__global__ void k_applyA1(const float* __restrict__ c0,
                          const float* __restrict__ scl, const float* __restrict__ bia,
                          u16* __restrict__ a1) {
  size_t i4 = ((size_t)blockIdx.x * 256 + threadIdx.x) * 4;
  int n = (int)(i4 & 1023);
  float4 v0 = *(const float4*)(c0 + i4);
  ushort4 o;
  o.x = f2bf(fmaxf(fmaf(v0.x, scl[n + 0], bia[n + 0]), 0.f));
  o.y = f2bf(fmaxf(fmaf(v0.y, scl[n + 1], bia[n + 1]), 0.f));
  o.z = f2bf(fmaxf(fmaf(v0.z, scl[n + 2], bia[n + 2]), 0.f));
  o.w = f2bf(fmaxf(fmaf(v0.w, scl[n + 3], bia[n + 3]), 0.f));
  *(ushort4*)(a1 + i4) = o;
}

// -------- y[b] = out_b + sum_n relu(h*scl+bia)*out_w[n] --------
__global__ void k_final(const float* __restrict__ h, const float* __restrict__ scl,
                        const float* __restrict__ bia, const float* __restrict__ ow,
                        const float* __restrict__ ob, float* __restrict__ y) {
  int lane = threadIdx.x & 63, wid = threadIdx.x >> 6;
  int row = blockIdx.x * 4 + wid;
  const float* hr = h + (size_t)row * 1024;
  float part = 0.f;
#pragma unroll
  for (int j = 0; j < 16; ++j) {
    int n = j * 64 + lane;
    float v = fmaxf(fmaf(hr[n], scl[n], bia[n]), 0.f);
    part = fmaf(v, ow[n], part);
  }
#pragma unroll
  for (int off = 32; off >= 1; off >>= 1) part += __shfl_xor(part, off);
  if (lane == 0) y[row] = part + ob[0];
}

extern "C" void kernel_launch(void* const* d_in, const int* in_sizes, int n_in,
                              void* d_out, int out_size, void* d_ws, size_t ws_size,
                              hipStream_t stream) {
  const int*   ids   = (const int*)d_in[0];
  const float* vals  = (const float*)d_in[1];
  const float* etab  = (const float*)d_in[2];
  const float* wb    = (const float*)d_in[3];
  const float* query = (const float*)d_in[4];
  const float* att   = (const float*)d_in[5];
  const float* bng   = (const float*)d_in[6];
  const float* w0    = (const float*)d_in[8];
  const float* g0    = (const float*)d_in[10];
  const float* be0   = (const float*)d_in[11];
  const float* w1    = (const float*)d_in[12];
  const float* g1    = (const float*)d_in[14];
  const float* be1   = (const float*)d_in[15];
  const float* outw  = (const float*)d_in[16];
  const float* outb  = (const float*)d_in[17];
  float* y = (float*)d_out;

  // workspace layout (peak ~195.6 MB):
  //   [0, 32K)            mt
  //   [32K, 33.59M)       w0bf (32MB, pre-scaled by arm-BN scl)
  //   [33.59M, 35.68M)    w1bf (2MB)
  //   [35.68M, 102.79M)   tbuf (64MB bf16)  -- alive through gemm0 (A operand)
  //   [102.79M, 136.35M)  c01 (4x8MB f32)   -- gemm0 partials; dead after red_stats<4>
  //   [102.79M, 136.35M)  h1 (4x8MB f32)    -- overlays dead c01; gemm1 partials
  //   [136.35M, +64K)     pstatB2 (stage-A o-stats)
  //   [169.90M, 178.29M)  r0 (8MB f32)
  //   [178.29M, 182.48M)  a1 (4MB bf16)
  //   [182.48M, 186.68M)  pstatB (4MB, per-block o-stats)
  //   [186.68M, 195.07M)  h (8MB f32, summed)
  //   [195.07M, ...)      pstat1/pstat2 + BN scalars
  char* ws = (char*)d_ws;
  u16*   mt     = (u16*)(ws + 0);
  u16*   w0bf   = (u16*)(ws + 32768ull);
  u16*   w1bf   = (u16*)(ws + 33587200ull);
  u16*   tbuf   = (u16*)(ws + 35684352ull);
  float* c01    = (float*)(ws + 102793216ull);
  float* h1     = (float*)(ws + 102793216ull);
  float* pstatB2= (float*)(ws + 136347648ull);
  float* r0     = (float*)(ws + 169902080ull);
  u16*   a1     = (u16*)(ws + 178290688ull);
  float* pstatB = (float*)(ws + 182484992ull);
  float* h      = (float*)(ws + 186679296ull);
  float* pstat1 = (float*)(ws + 195067904ull);
  float* pstat2 = (float*)(ws + 195330048ull);
  float* sclA   = (float*)(ws + 195608576ull);
  float* scl1   = (float*)(ws + 195609600ull);
  float* bia1   = (float*)(ws + 195613696ull);
  float* scl2   = (float*)(ws + 195617792ull);
  float* bia2   = (float*)(ws + 195621888ull);

  k_prep<<<1088, 256, 0, stream>>>(wb, query, mt, w1, w1bf);
  k_mega<<<2048, 256, 0, stream>>>(ids, vals, etab, mt, att, tbuf, pstatB);
  k_stats_oA<<<32, 256, 0, stream>>>(pstatB, pstatB2);
  k_stats_o_finB<<<1, 256, 0, stream>>>(pstatB2, bng, sclA);
  k_cvt_w0s<<<16384, 256, 0, stream>>>(w0, sclA, w0bf);
  // gemm0: ring-4 (64KB, 2/CU), 2-tile-per-sync, split-K=4 -> 512 blocks, ksz=4096 (nkt=128)
  k_gemmp<<<dim3(16, 8, 4), 256, 0, stream>>>(tbuf, w0bf, c01, 2048, 1024, 16384, 4096);
  k_red_stats<4><<<dim3(16, 32), 256, 0, stream>>>(c01, r0, pstat1);
  k_stats_fin<<<4, 256, 0, stream>>>(pstat1, g0, be0, scl1, bia1);
  k_applyA1<<<2048, 256, 0, stream>>>(r0, scl1, bia1, a1);
  // gemm1: same kernel, split-K=4 -> 512 blocks, ksz=256 (nkt=8)
  k_gemmp<<<dim3(16, 8, 4), 256, 0, stream>>>(a1, w1bf, h1, 2048, 1024, 1024, 256);
  k_red_stats<4><<<dim3(16, 32), 256, 0, stream>>>(h1, h, pstat2);
  k_stats_fin<<<4, 256, 0, stream>>>(pstat2, g1, be1, scl2, bia2);
  k_final<<<512, 256, 0, stream>>>(h, scl2, bia2, outw, outb, y);
}